// Round 1
// baseline (343.821 us; speedup 1.0000x reference)
//
#include <hip/hip_runtime.h>
#include <hip/hip_bf16.h>
#include <math.h>

// ---------------------------------------------------------------------------
// LeNet-ish forward:
//  img (16,3,512,512) fp32
//  I = mean_c(img); x = concat(img, I)  [folded into conv1 weights]
//  conv1 5x5 VALID (4->6) + sigmoid + maxpool2  -> (16,6,254,254)
//  conv2 5x5 VALID (6->16) + sigmoid + maxpool2 -> (16,16,125,125)
//  fc0 (250000->120) sigmoid, fc1 (120->84) sigmoid, fc2 (84->10)
//  g1=out[:,0]+gb1, g2=out[:,1]+gb2, gain=sum(out[:,2:]+base1)
//  out = where(I<=0.5, clip(img*gain,EPS,1)^g1, ...^g2)
// Scratch layout inside d_out (float):
//  [0)                act1   6,193,536
//  [6,193,536)        act2   4,000,000
//  [10,193,536)       fc0 partials 489*1920 = 938,880
//  [11,132,416)       h0     1,920
// d_ws: params g1[16], g2[16], gain[16]  (192 bytes)
// ---------------------------------------------------------------------------

#define EPSF 1e-8f

__device__ __forceinline__ float sigmf(float x) {
    return 1.0f / (1.0f + __expf(-x));
}

// ---------------- conv1 + sigmoid + maxpool ----------------
// grid (16,16,16), block (16,16). Pooled tile 16x16 per block.
__global__ __launch_bounds__(256) void k_conv1(const float* __restrict__ img,
                                               const float* __restrict__ w,
                                               const float* __restrict__ bias,
                                               float* __restrict__ act1) {
    __shared__ float sIn[3][36][37];
    __shared__ float sW[6][3][25];
    __shared__ float sB[6];
    const int bx = blockIdx.x, by = blockIdx.y, bb = blockIdx.z;
    const int tx = threadIdx.x, ty = threadIdx.y;
    const int tid = ty * 16 + tx;

    if (tid < 450) {
        int oc = tid / 75, r = tid % 75, ic = r / 25, k = r % 25;
        // fold channel-3 (gray = mean of 3) into the 3 real channels
        sW[oc][ic][k] = w[(oc * 4 + ic) * 25 + k] + w[(oc * 4 + 3) * 25 + k] * (1.0f / 3.0f);
    }
    if (tid < 6) sB[tid] = bias[tid];

    const int iy0 = by * 32, ix0 = bx * 32;
    for (int ic = 0; ic < 3; ++ic) {
        const float* ip = img + ((size_t)bb * 3 + ic) * 512 * 512;
        for (int i = tid; i < 36 * 36; i += 256) {
            int r = i / 36, c = i % 36;
            int gy = iy0 + r, gx = ix0 + c;
            sIn[ic][r][c] = (gy < 512 && gx < 512) ? ip[gy * 512 + gx] : 0.0f;
        }
    }
    __syncthreads();

    float acc[6][4];
#pragma unroll
    for (int oc = 0; oc < 6; ++oc) {
        float bv = sB[oc];
        acc[oc][0] = bv; acc[oc][1] = bv; acc[oc][2] = bv; acc[oc][3] = bv;
    }

    for (int ic = 0; ic < 3; ++ic) {
        float win[6][6];
#pragma unroll
        for (int r = 0; r < 6; ++r)
#pragma unroll
            for (int c = 0; c < 6; ++c) win[r][c] = sIn[ic][2 * ty + r][2 * tx + c];
#pragma unroll
        for (int oc = 0; oc < 6; ++oc)
#pragma unroll
            for (int ky = 0; ky < 5; ++ky)
#pragma unroll
                for (int kx = 0; kx < 5; ++kx) {
                    float wv = sW[oc][ic][ky * 5 + kx];
                    acc[oc][0] = fmaf(wv, win[ky][kx], acc[oc][0]);
                    acc[oc][1] = fmaf(wv, win[ky][kx + 1], acc[oc][1]);
                    acc[oc][2] = fmaf(wv, win[ky + 1][kx], acc[oc][2]);
                    acc[oc][3] = fmaf(wv, win[ky + 1][kx + 1], acc[oc][3]);
                }
    }

    const int py = by * 16 + ty, px = bx * 16 + tx;
    if (py < 254 && px < 254) {
#pragma unroll
        for (int oc = 0; oc < 6; ++oc) {
            float m = fmaxf(fmaxf(acc[oc][0], acc[oc][1]), fmaxf(acc[oc][2], acc[oc][3]));
            act1[(((size_t)bb * 6 + oc) * 254 + py) * 254 + px] = sigmf(m);
        }
    }
}

// ---------------- conv2 + sigmoid + maxpool ----------------
// grid (8,8,32): z = batch*2 + oc_group. block (16,16).
__global__ __launch_bounds__(256) void k_conv2(const float* __restrict__ act1,
                                               const float* __restrict__ w,
                                               const float* __restrict__ bias,
                                               float* __restrict__ act2) {
    __shared__ float sIn[6][36][37];
    __shared__ float sW[8][6][25];
    __shared__ float sB[8];
    const int bx = blockIdx.x, by = blockIdx.y;
    const int bb = blockIdx.z >> 1, og = (blockIdx.z & 1) * 8;
    const int tx = threadIdx.x, ty = threadIdx.y;
    const int tid = ty * 16 + tx;

    for (int i = tid; i < 8 * 6 * 25; i += 256) {
        int oc = i / 150, r = i % 150, ic = r / 25, k = r % 25;
        sW[oc][ic][k] = w[((og + oc) * 6 + ic) * 25 + k];
    }
    if (tid < 8) sB[tid] = bias[og + tid];

    const int iy0 = by * 32, ix0 = bx * 32;
    for (int ic = 0; ic < 6; ++ic) {
        const float* ip = act1 + ((size_t)bb * 6 + ic) * 254 * 254;
        for (int i = tid; i < 36 * 36; i += 256) {
            int r = i / 36, c = i % 36;
            int gy = iy0 + r, gx = ix0 + c;
            sIn[ic][r][c] = (gy < 254 && gx < 254) ? ip[gy * 254 + gx] : 0.0f;
        }
    }
    __syncthreads();

    float acc[8][4];
#pragma unroll
    for (int oc = 0; oc < 8; ++oc) {
        float bv = sB[oc];
        acc[oc][0] = bv; acc[oc][1] = bv; acc[oc][2] = bv; acc[oc][3] = bv;
    }

    for (int ic = 0; ic < 6; ++ic) {
        float win[6][6];
#pragma unroll
        for (int r = 0; r < 6; ++r)
#pragma unroll
            for (int c = 0; c < 6; ++c) win[r][c] = sIn[ic][2 * ty + r][2 * tx + c];
#pragma unroll
        for (int oc = 0; oc < 8; ++oc)
#pragma unroll
            for (int ky = 0; ky < 5; ++ky)
#pragma unroll
                for (int kx = 0; kx < 5; ++kx) {
                    float wv = sW[oc][ic][ky * 5 + kx];
                    acc[oc][0] = fmaf(wv, win[ky][kx], acc[oc][0]);
                    acc[oc][1] = fmaf(wv, win[ky][kx + 1], acc[oc][1]);
                    acc[oc][2] = fmaf(wv, win[ky + 1][kx], acc[oc][2]);
                    acc[oc][3] = fmaf(wv, win[ky + 1][kx + 1], acc[oc][3]);
                }
    }

    const int py = by * 16 + ty, px = bx * 16 + tx;
    if (py < 125 && px < 125) {
#pragma unroll
        for (int oc = 0; oc < 8; ++oc) {
            float m = fmaxf(fmaxf(acc[oc][0], acc[oc][1]), fmaxf(acc[oc][2], acc[oc][3]));
            act2[(((size_t)bb * 16 + og + oc) * 125 + py) * 125 + px] = sigmf(m);
        }
    }
}

// ---------------- fc0 partials ----------------
// X = act2 flat (16,250000); W = fc0_w (120,250000).
// K_BLK=512 per block, 489 blocks. Wave covers 128 k, lane(s=l>>4,b=l&15)
// covers 32 k. W loads: same address across the 16 b-lanes -> broadcast.
#define FC0_KBLK 512
#define FC0_NB   489  // ceil(250000/512)

__global__ __launch_bounds__(256) void k_fc0(const float* __restrict__ x,
                                             const float* __restrict__ w,
                                             float* __restrict__ partial) {
    __shared__ float sX[16][516];
    __shared__ float sRed[4][1920];
    const int blk = blockIdx.x;
    const int k0 = blk * FC0_KBLK;
    const int tid = threadIdx.x;
    const int valid = min(FC0_KBLK, 250000 - k0);

    for (int i = tid; i < 16 * FC0_KBLK; i += 256) {
        int bb = i >> 9, k = i & 511;
        sX[bb][k] = (k < valid) ? x[(size_t)bb * 250000 + k0 + k] : 0.0f;
    }
    __syncthreads();

    const int wv = tid >> 6, l = tid & 63;
    const int s = l >> 4, bb = l & 15;
    const int kb = wv * 128 + s * 32;  // lane k base within block chunk

    float4 xr[8];
#pragma unroll
    for (int j = 0; j < 8; ++j) xr[j] = *(const float4*)&sX[bb][kb + 4 * j];

    int koff[8];
#pragma unroll
    for (int j = 0; j < 8; ++j) koff[j] = min(kb + 4 * j, 250000 - 4 - k0);

    for (int o = 0; o < 120; ++o) {
        const float* wr = w + (size_t)o * 250000 + k0;
        float a = 0.0f;
#pragma unroll
        for (int j = 0; j < 8; ++j) {
            float4 w4 = *(const float4*)(wr + koff[j]);
            a = fmaf(xr[j].x, w4.x, a);
            a = fmaf(xr[j].y, w4.y, a);
            a = fmaf(xr[j].z, w4.z, a);
            a = fmaf(xr[j].w, w4.w, a);
        }
        a += __shfl_xor(a, 16);
        a += __shfl_xor(a, 32);
        if (s == 0) sRed[wv][bb * 120 + o] = a;
    }
    __syncthreads();

    for (int i = tid; i < 1920; i += 256) {
        float v = sRed[0][i] + sRed[1][i] + sRed[2][i] + sRed[3][i];
        partial[(size_t)blk * 1920 + i] = v;
    }
}

// ---------------- fc0 reduce + bias + sigmoid ----------------
__global__ __launch_bounds__(256) void k_fc0red(const float* __restrict__ partial,
                                                const float* __restrict__ b0,
                                                float* __restrict__ h0) {
    int bo = blockIdx.x * 256 + threadIdx.x;
    if (bo >= 1920) return;
    float s = 0.0f;
    for (int blk = 0; blk < FC0_NB; ++blk) s += partial[(size_t)blk * 1920 + bo];
    int o = bo % 120;
    h0[bo] = sigmf(s + b0[o]);
}

// ---------------- fc1 + fc2 + gamma/gain params ----------------
__global__ __launch_bounds__(256) void k_fctail(const float* __restrict__ h0in,
                                                const float* __restrict__ fc1_w,
                                                const float* __restrict__ fc1_b,
                                                const float* __restrict__ fc2_w,
                                                const float* __restrict__ fc2_b,
                                                const float* __restrict__ gb1,
                                                const float* __restrict__ gb2,
                                                const float* __restrict__ base1,
                                                float* __restrict__ params) {
    __shared__ float sh0[1920];
    __shared__ float sh1[16][84];
    __shared__ float sout[16][10];
    const int tid = threadIdx.x;

    for (int i = tid; i < 1920; i += 256) sh0[i] = h0in[i];
    __syncthreads();

    for (int i = tid; i < 16 * 84; i += 256) {
        int b = i / 84, o = i % 84;
        float a = fc1_b[o];
        for (int k = 0; k < 120; ++k) a = fmaf(sh0[b * 120 + k], fc1_w[o * 120 + k], a);
        sh1[b][o] = sigmf(a);
    }
    __syncthreads();

    for (int i = tid; i < 160; i += 256) {
        int b = i / 10, o = i % 10;
        float a = fc2_b[o];
        for (int k = 0; k < 84; ++k) a = fmaf(sh1[b][k], fc2_w[o * 84 + k], a);
        sout[b][o] = a;
    }
    __syncthreads();

    if (tid < 16) {
        int b = tid;
        float g1 = sout[b][0] + gb1[0];
        float g2 = sout[b][1] + gb2[0];
        float gain = 0.0f;
        for (int j = 0; j < 8; ++j) gain += sout[b][2 + j] + base1[j];
        params[b] = g1;
        params[16 + b] = g2;
        params[32 + b] = gain;
    }
}

// ---------------- final: mask + clip + pow ----------------
__global__ __launch_bounds__(256) void k_final(const float* __restrict__ img,
                                               const float* __restrict__ params,
                                               float* __restrict__ out) {
    int idx = blockIdx.x * 256 + threadIdx.x;  // b*262144 + h*512 + w
    int b = idx >> 18;
    int hw = idx & 262143;
    size_t base = ((size_t)b * 3) * 262144 + hw;

    float r = img[base];
    float g = img[base + 262144];
    float bl = img[base + 2 * 262144];
    float I = (r + g + bl) * (1.0f / 3.0f);
    float gv = (I > 0.5f) ? params[16 + b] : params[b];
    float gain = params[32 + b];

    float v0 = fminf(fmaxf(r * gain, EPSF), 1.0f);
    float v1 = fminf(fmaxf(g * gain, EPSF), 1.0f);
    float v2 = fminf(fmaxf(bl * gain, EPSF), 1.0f);

    out[base] = __powf(v0, gv);
    out[base + 262144] = __powf(v1, gv);
    out[base + 2 * 262144] = __powf(v2, gv);
}

// ---------------------------------------------------------------------------
extern "C" void kernel_launch(void* const* d_in, const int* in_sizes, int n_in,
                              void* d_out, int out_size, void* d_ws, size_t ws_size,
                              hipStream_t stream) {
    const float* img     = (const float*)d_in[0];
    const float* conv1_w = (const float*)d_in[1];
    const float* conv1_b = (const float*)d_in[2];
    const float* conv2_w = (const float*)d_in[3];
    const float* conv2_b = (const float*)d_in[4];
    const float* fc0_w   = (const float*)d_in[5];
    const float* fc0_b   = (const float*)d_in[6];
    const float* fc1_w   = (const float*)d_in[7];
    const float* fc1_b   = (const float*)d_in[8];
    const float* fc2_w   = (const float*)d_in[9];
    const float* fc2_b   = (const float*)d_in[10];
    const float* gb1     = (const float*)d_in[11];
    const float* gb2     = (const float*)d_in[12];
    const float* base1   = (const float*)d_in[13];

    float* outp = (float*)d_out;
    // scratch carved out of d_out (final kernel overwrites everything)
    float* act1    = outp;                      // 6,193,536
    float* act2    = outp + 6193536;            // 4,000,000
    float* partial = outp + 10193536;           // 489*1920 = 938,880
    float* h0      = outp + 11132416;           // 1,920
    float* params  = (float*)d_ws;              // 48 floats

    k_conv1<<<dim3(16, 16, 16), dim3(16, 16), 0, stream>>>(img, conv1_w, conv1_b, act1);
    k_conv2<<<dim3(8, 8, 32), dim3(16, 16), 0, stream>>>(act1, conv2_w, conv2_b, act2);
    k_fc0<<<dim3(FC0_NB), dim3(256), 0, stream>>>(act2, fc0_w, partial);
    k_fc0red<<<dim3(8), dim3(256), 0, stream>>>(partial, fc0_b, h0);
    k_fctail<<<dim3(1), dim3(256), 0, stream>>>(h0, fc1_w, fc1_b, fc2_w, fc2_b,
                                                gb1, gb2, base1, params);
    k_final<<<dim3(16384), dim3(256), 0, stream>>>(img, params, outp);
}

// Round 2
// 301.663 us; speedup vs baseline: 1.1398x; 1.1398x over previous
//
#include <hip/hip_runtime.h>
#include <hip/hip_bf16.h>
#include <math.h>

// ---------------------------------------------------------------------------
// LeNet-ish forward. Scratch inside d_out (float):
//  [0)          act1   6,193,536
//  [6,193,536)  act2   4,000,000
//  [10,193,536) fc0 partials 489*1920 = 938,880
//  [11,132,416) h0     1,920
// d_ws: params g1[16], g2[16], gain[16]  (192 bytes)
// ---------------------------------------------------------------------------

#define EPSF 1e-8f

__device__ __forceinline__ float sigmf(float x) {
    return 1.0f / (1.0f + __expf(-x));
}

// ---------------- conv1 + sigmoid + maxpool ----------------
__global__ __launch_bounds__(256) void k_conv1(const float* __restrict__ img,
                                               const float* __restrict__ w,
                                               const float* __restrict__ bias,
                                               float* __restrict__ act1) {
    __shared__ float sIn[3][36][37];
    __shared__ float sW[6][3][25];
    __shared__ float sB[6];
    const int bx = blockIdx.x, by = blockIdx.y, bb = blockIdx.z;
    const int tx = threadIdx.x, ty = threadIdx.y;
    const int tid = ty * 16 + tx;

    if (tid < 450) {
        int oc = tid / 75, r = tid % 75, ic = r / 25, k = r % 25;
        sW[oc][ic][k] = w[(oc * 4 + ic) * 25 + k] + w[(oc * 4 + 3) * 25 + k] * (1.0f / 3.0f);
    }
    if (tid < 6) sB[tid] = bias[tid];

    const int iy0 = by * 32, ix0 = bx * 32;
    for (int ic = 0; ic < 3; ++ic) {
        const float* ip = img + ((size_t)bb * 3 + ic) * 512 * 512;
        for (int i = tid; i < 36 * 36; i += 256) {
            int r = i / 36, c = i % 36;
            int gy = iy0 + r, gx = ix0 + c;
            sIn[ic][r][c] = (gy < 512 && gx < 512) ? ip[gy * 512 + gx] : 0.0f;
        }
    }
    __syncthreads();

    float acc[6][4];
#pragma unroll
    for (int oc = 0; oc < 6; ++oc) {
        float bv = sB[oc];
        acc[oc][0] = bv; acc[oc][1] = bv; acc[oc][2] = bv; acc[oc][3] = bv;
    }

    for (int ic = 0; ic < 3; ++ic) {
        float win[6][6];
#pragma unroll
        for (int r = 0; r < 6; ++r)
#pragma unroll
            for (int c = 0; c < 6; ++c) win[r][c] = sIn[ic][2 * ty + r][2 * tx + c];
#pragma unroll
        for (int oc = 0; oc < 6; ++oc)
#pragma unroll
            for (int ky = 0; ky < 5; ++ky)
#pragma unroll
                for (int kx = 0; kx < 5; ++kx) {
                    float wv = sW[oc][ic][ky * 5 + kx];
                    acc[oc][0] = fmaf(wv, win[ky][kx], acc[oc][0]);
                    acc[oc][1] = fmaf(wv, win[ky][kx + 1], acc[oc][1]);
                    acc[oc][2] = fmaf(wv, win[ky + 1][kx], acc[oc][2]);
                    acc[oc][3] = fmaf(wv, win[ky + 1][kx + 1], acc[oc][3]);
                }
    }

    const int py = by * 16 + ty, px = bx * 16 + tx;
    if (py < 254 && px < 254) {
#pragma unroll
        for (int oc = 0; oc < 6; ++oc) {
            float m = fmaxf(fmaxf(acc[oc][0], acc[oc][1]), fmaxf(acc[oc][2], acc[oc][3]));
            act1[(((size_t)bb * 6 + oc) * 254 + py) * 254 + px] = sigmf(m);
        }
    }
}

// ---------------- conv2 + sigmoid + maxpool ----------------
__global__ __launch_bounds__(256) void k_conv2(const float* __restrict__ act1,
                                               const float* __restrict__ w,
                                               const float* __restrict__ bias,
                                               float* __restrict__ act2) {
    __shared__ float sIn[6][36][37];
    __shared__ float sW[8][6][25];
    __shared__ float sB[8];
    const int bx = blockIdx.x, by = blockIdx.y;
    const int bb = blockIdx.z >> 1, og = (blockIdx.z & 1) * 8;
    const int tx = threadIdx.x, ty = threadIdx.y;
    const int tid = ty * 16 + tx;

    for (int i = tid; i < 8 * 6 * 25; i += 256) {
        int oc = i / 150, r = i % 150, ic = r / 25, k = r % 25;
        sW[oc][ic][k] = w[((og + oc) * 6 + ic) * 25 + k];
    }
    if (tid < 8) sB[tid] = bias[og + tid];

    const int iy0 = by * 32, ix0 = bx * 32;
    for (int ic = 0; ic < 6; ++ic) {
        const float* ip = act1 + ((size_t)bb * 6 + ic) * 254 * 254;
        for (int i = tid; i < 36 * 36; i += 256) {
            int r = i / 36, c = i % 36;
            int gy = iy0 + r, gx = ix0 + c;
            sIn[ic][r][c] = (gy < 254 && gx < 254) ? ip[gy * 254 + gx] : 0.0f;
        }
    }
    __syncthreads();

    float acc[8][4];
#pragma unroll
    for (int oc = 0; oc < 8; ++oc) {
        float bv = sB[oc];
        acc[oc][0] = bv; acc[oc][1] = bv; acc[oc][2] = bv; acc[oc][3] = bv;
    }

    for (int ic = 0; ic < 6; ++ic) {
        float win[6][6];
#pragma unroll
        for (int r = 0; r < 6; ++r)
#pragma unroll
            for (int c = 0; c < 6; ++c) win[r][c] = sIn[ic][2 * ty + r][2 * tx + c];
#pragma unroll
        for (int oc = 0; oc < 8; ++oc)
#pragma unroll
            for (int ky = 0; ky < 5; ++ky)
#pragma unroll
                for (int kx = 0; kx < 5; ++kx) {
                    float wv = sW[oc][ic][ky * 5 + kx];
                    acc[oc][0] = fmaf(wv, win[ky][kx], acc[oc][0]);
                    acc[oc][1] = fmaf(wv, win[ky][kx + 1], acc[oc][1]);
                    acc[oc][2] = fmaf(wv, win[ky + 1][kx], acc[oc][2]);
                    acc[oc][3] = fmaf(wv, win[ky + 1][kx + 1], acc[oc][3]);
                }
    }

    const int py = by * 16 + ty, px = bx * 16 + tx;
    if (py < 125 && px < 125) {
#pragma unroll
        for (int oc = 0; oc < 8; ++oc) {
            float m = fmaxf(fmaxf(acc[oc][0], acc[oc][1]), fmaxf(acc[oc][2], acc[oc][3]));
            act2[(((size_t)bb * 16 + og + oc) * 125 + py) * 125 + px] = sigmf(m);
        }
    }
}

// ---------------- fc0 partials (rewritten, latency-optimized) ----------------
// X = act2 flat (16,250000); W = fc0_w (120,250000). y[b][o] = sum_k X W.
// Block = 256 thr = 4 waves; block k-span 512, wave k-span 128.
// Lane l: s = l&7 (k-slice), b2 = l>>3 (batch pair {2*b2, 2*b2+1}).
// Per o: 4 coalesced float4 W loads (8 lanes contiguous = 128B, 8x broadcast),
// 32 FMA, 6 shfl_xor, float2 LDS store. X lives in 32 VGPRs, loaded once.
#define FC0_KBLK 512
#define FC0_NB   489  // ceil(250000/512); 488*512=249856, tail 144

__global__ __launch_bounds__(256) void k_fc0(const float* __restrict__ x,
                                             const float* __restrict__ w,
                                             float* __restrict__ partial) {
    __shared__ float sY[4][120][16];
    const int tid = threadIdx.x;
    const int wv = tid >> 6, l = tid & 63;
    const int s = l & 7, b2 = l >> 3;
    const int kw = blockIdx.x * FC0_KBLK + wv * 128;  // wave k-base

    // per-thread k offsets: kj = kw + j*32 + s*4  (j=0..3)
    int koff[4];
    bool inb[4];
#pragma unroll
    for (int j = 0; j < 4; ++j) {
        int kj = kw + j * 32 + s * 4;
        inb[j] = (kj < 250000);               // float4 fully in iff kj < 250000 (250000%4==0)
        koff[j] = inb[j] ? kj : 249996;       // clamp (value unused when X=0)
    }

    // X registers: 2 batches x 4 float4
    const int b0i = b2 * 2;
    float4 xr[2][4];
#pragma unroll
    for (int bi = 0; bi < 2; ++bi) {
        const float* xp = x + (size_t)(b0i + bi) * 250000;
#pragma unroll
        for (int j = 0; j < 4; ++j) {
            if (inb[j]) xr[bi][j] = *(const float4*)(xp + koff[j]);
            else xr[bi][j] = make_float4(0.f, 0.f, 0.f, 0.f);
        }
    }

    for (int o = 0; o < 120; ++o) {
        const float* row = w + (size_t)o * 250000;
        float a0 = 0.0f, a1 = 0.0f;
#pragma unroll
        for (int j = 0; j < 4; ++j) {
            float4 w4 = *(const float4*)(row + koff[j]);
            a0 = fmaf(xr[0][j].x, w4.x, a0);
            a0 = fmaf(xr[0][j].y, w4.y, a0);
            a0 = fmaf(xr[0][j].z, w4.z, a0);
            a0 = fmaf(xr[0][j].w, w4.w, a0);
            a1 = fmaf(xr[1][j].x, w4.x, a1);
            a1 = fmaf(xr[1][j].y, w4.y, a1);
            a1 = fmaf(xr[1][j].z, w4.z, a1);
            a1 = fmaf(xr[1][j].w, w4.w, a1);
        }
        // reduce over s (low 3 lane bits)
        a0 += __shfl_xor(a0, 1); a1 += __shfl_xor(a1, 1);
        a0 += __shfl_xor(a0, 2); a1 += __shfl_xor(a1, 2);
        a0 += __shfl_xor(a0, 4); a1 += __shfl_xor(a1, 4);
        if (s == 0) {
            sY[wv][o][b0i] = a0;
            sY[wv][o][b0i + 1] = a1;
        }
    }
    __syncthreads();

    // cross-wave reduce -> partial[blk][o*16+b]
    float* pp = partial + (size_t)blockIdx.x * 1920;
    for (int i = tid; i < 1920; i += 256) {
        pp[i] = sY[0][i >> 4][i & 15] + sY[1][i >> 4][i & 15] +
                sY[2][i >> 4][i & 15] + sY[3][i >> 4][i & 15];
    }
}

// ---------------- fc0 reduce + bias + sigmoid ----------------
// partial layout: [489][o*16+b]. One wave per (o,b); h0[b*120+o].
__global__ __launch_bounds__(256) void k_fc0red(const float* __restrict__ partial,
                                                const float* __restrict__ b0,
                                                float* __restrict__ h0) {
    const int tid = threadIdx.x;
    const int wv = tid >> 6, l = tid & 63;
    const int i = blockIdx.x * 4 + wv;  // 0..1919 = o*16+b
    float s = 0.0f;
    for (int c = l; c < FC0_NB; c += 64) s += partial[(size_t)c * 1920 + i];
    s += __shfl_xor(s, 1);
    s += __shfl_xor(s, 2);
    s += __shfl_xor(s, 4);
    s += __shfl_xor(s, 8);
    s += __shfl_xor(s, 16);
    s += __shfl_xor(s, 32);
    if (l == 0) {
        int o = i >> 4, b = i & 15;
        h0[b * 120 + o] = sigmf(s + b0[o]);
    }
}

// ---------------- fc1 + fc2 + gamma/gain params ----------------
__global__ __launch_bounds__(256) void k_fctail(const float* __restrict__ h0in,
                                                const float* __restrict__ fc1_w,
                                                const float* __restrict__ fc1_b,
                                                const float* __restrict__ fc2_w,
                                                const float* __restrict__ fc2_b,
                                                const float* __restrict__ gb1,
                                                const float* __restrict__ gb2,
                                                const float* __restrict__ base1,
                                                float* __restrict__ params) {
    __shared__ float sh0[1920];
    __shared__ float sh1[16][84];
    __shared__ float sout[16][10];
    const int tid = threadIdx.x;

    for (int i = tid; i < 1920; i += 256) sh0[i] = h0in[i];
    __syncthreads();

    for (int i = tid; i < 16 * 84; i += 256) {
        int b = i / 84, o = i % 84;
        float a = fc1_b[o];
        for (int k = 0; k < 120; ++k) a = fmaf(sh0[b * 120 + k], fc1_w[o * 120 + k], a);
        sh1[b][o] = sigmf(a);
    }
    __syncthreads();

    for (int i = tid; i < 160; i += 256) {
        int b = i / 10, o = i % 10;
        float a = fc2_b[o];
        for (int k = 0; k < 84; ++k) a = fmaf(sh1[b][k], fc2_w[o * 84 + k], a);
        sout[b][o] = a;
    }
    __syncthreads();

    if (tid < 16) {
        int b = tid;
        float g1 = sout[b][0] + gb1[0];
        float g2 = sout[b][1] + gb2[0];
        float gain = 0.0f;
        for (int j = 0; j < 8; ++j) gain += sout[b][2 + j] + base1[j];
        params[b] = g1;
        params[16 + b] = g2;
        params[32 + b] = gain;
    }
}

// ---------------- final: mask + clip + pow (float4) ----------------
__global__ __launch_bounds__(256) void k_final(const float* __restrict__ img,
                                               const float* __restrict__ params,
                                               float* __restrict__ out) {
    int idx = blockIdx.x * 256 + threadIdx.x;  // group of 4 pixels
    int p = idx * 4;
    int b = p >> 18;
    int hw = p & 262143;
    size_t base = ((size_t)b * 3) * 262144 + hw;

    float4 r = *(const float4*)(img + base);
    float4 g = *(const float4*)(img + base + 262144);
    float4 bl = *(const float4*)(img + base + 2 * 262144);
    float g1 = params[b], g2 = params[16 + b], gain = params[32 + b];

    float4 o0, o1, o2;
#pragma unroll
    for (int e = 0; e < 4; ++e) {
        float re = (&r.x)[e], ge = (&g.x)[e], be = (&bl.x)[e];
        float I = (re + ge + be) * (1.0f / 3.0f);
        float gv = (I > 0.5f) ? g2 : g1;
        (&o0.x)[e] = __powf(fminf(fmaxf(re * gain, EPSF), 1.0f), gv);
        (&o1.x)[e] = __powf(fminf(fmaxf(ge * gain, EPSF), 1.0f), gv);
        (&o2.x)[e] = __powf(fminf(fmaxf(be * gain, EPSF), 1.0f), gv);
    }
    *(float4*)(out + base) = o0;
    *(float4*)(out + base + 262144) = o1;
    *(float4*)(out + base + 2 * 262144) = o2;
}

// ---------------------------------------------------------------------------
extern "C" void kernel_launch(void* const* d_in, const int* in_sizes, int n_in,
                              void* d_out, int out_size, void* d_ws, size_t ws_size,
                              hipStream_t stream) {
    const float* img     = (const float*)d_in[0];
    const float* conv1_w = (const float*)d_in[1];
    const float* conv1_b = (const float*)d_in[2];
    const float* conv2_w = (const float*)d_in[3];
    const float* conv2_b = (const float*)d_in[4];
    const float* fc0_w   = (const float*)d_in[5];
    const float* fc0_b   = (const float*)d_in[6];
    const float* fc1_w   = (const float*)d_in[7];
    const float* fc1_b   = (const float*)d_in[8];
    const float* fc2_w   = (const float*)d_in[9];
    const float* fc2_b   = (const float*)d_in[10];
    const float* gb1     = (const float*)d_in[11];
    const float* gb2     = (const float*)d_in[12];
    const float* base1   = (const float*)d_in[13];

    float* outp = (float*)d_out;
    float* act1    = outp;                      // 6,193,536
    float* act2    = outp + 6193536;            // 4,000,000
    float* partial = outp + 10193536;           // 489*1920 = 938,880
    float* h0      = outp + 11132416;           // 1,920
    float* params  = (float*)d_ws;              // 48 floats

    k_conv1<<<dim3(16, 16, 16), dim3(16, 16), 0, stream>>>(img, conv1_w, conv1_b, act1);
    k_conv2<<<dim3(8, 8, 32), dim3(16, 16), 0, stream>>>(act1, conv2_w, conv2_b, act2);
    k_fc0<<<dim3(FC0_NB), dim3(256), 0, stream>>>(act2, fc0_w, partial);
    k_fc0red<<<dim3(480), dim3(256), 0, stream>>>(partial, fc0_b, h0);
    k_fctail<<<dim3(1), dim3(256), 0, stream>>>(h0, fc1_w, fc1_b, fc2_w, fc2_b,
                                                gb1, gb2, base1, params);
    k_final<<<dim3(4096), dim3(256), 0, stream>>>(img, params, outp);
}

// Round 3
// 280.051 us; speedup vs baseline: 1.2277x; 1.0772x over previous
//
#include <hip/hip_runtime.h>
#include <hip/hip_bf16.h>
#include <math.h>

// ---------------------------------------------------------------------------
// LeNet-ish forward. Scratch inside d_out (float):
//  [0)          act1   6,193,536
//  [6,193,536)  act2   4,000,000
//  [10,193,536) fc0 partials 489*1920 = 938,880
//  [11,132,416) h0     1,920
// d_ws: params g1[16], g2[16], gain[16]  (192 bytes)
// ---------------------------------------------------------------------------

#define EPSF 1e-8f

__device__ __forceinline__ float sigmf(float x) {
    return 1.0f / (1.0f + __expf(-x));
}

// ---------------- conv1 + sigmoid + maxpool ----------------
__global__ __launch_bounds__(256) void k_conv1(const float* __restrict__ img,
                                               const float* __restrict__ w,
                                               const float* __restrict__ bias,
                                               float* __restrict__ act1) {
    __shared__ float sIn[3][36][37];
    __shared__ float sW[6][3][25];
    __shared__ float sB[6];
    const int bx = blockIdx.x, by = blockIdx.y, bb = blockIdx.z;
    const int tx = threadIdx.x, ty = threadIdx.y;
    const int tid = ty * 16 + tx;

    if (tid < 450) {
        int oc = tid / 75, r = tid % 75, ic = r / 25, k = r % 25;
        sW[oc][ic][k] = w[(oc * 4 + ic) * 25 + k] + w[(oc * 4 + 3) * 25 + k] * (1.0f / 3.0f);
    }
    if (tid < 6) sB[tid] = bias[tid];

    const int iy0 = by * 32, ix0 = bx * 32;
    for (int ic = 0; ic < 3; ++ic) {
        const float* ip = img + ((size_t)bb * 3 + ic) * 512 * 512;
        for (int i = tid; i < 36 * 36; i += 256) {
            int r = i / 36, c = i % 36;
            int gy = iy0 + r, gx = ix0 + c;
            sIn[ic][r][c] = (gy < 512 && gx < 512) ? ip[gy * 512 + gx] : 0.0f;
        }
    }
    __syncthreads();

    float acc[6][4];
#pragma unroll
    for (int oc = 0; oc < 6; ++oc) {
        float bv = sB[oc];
        acc[oc][0] = bv; acc[oc][1] = bv; acc[oc][2] = bv; acc[oc][3] = bv;
    }

    for (int ic = 0; ic < 3; ++ic) {
        float win[6][6];
#pragma unroll
        for (int r = 0; r < 6; ++r)
#pragma unroll
            for (int c = 0; c < 6; ++c) win[r][c] = sIn[ic][2 * ty + r][2 * tx + c];
#pragma unroll
        for (int oc = 0; oc < 6; ++oc)
#pragma unroll
            for (int ky = 0; ky < 5; ++ky)
#pragma unroll
                for (int kx = 0; kx < 5; ++kx) {
                    float wv = sW[oc][ic][ky * 5 + kx];
                    acc[oc][0] = fmaf(wv, win[ky][kx], acc[oc][0]);
                    acc[oc][1] = fmaf(wv, win[ky][kx + 1], acc[oc][1]);
                    acc[oc][2] = fmaf(wv, win[ky + 1][kx], acc[oc][2]);
                    acc[oc][3] = fmaf(wv, win[ky + 1][kx + 1], acc[oc][3]);
                }
    }

    const int py = by * 16 + ty, px = bx * 16 + tx;
    if (py < 254 && px < 254) {
#pragma unroll
        for (int oc = 0; oc < 6; ++oc) {
            float m = fmaxf(fmaxf(acc[oc][0], acc[oc][1]), fmaxf(acc[oc][2], acc[oc][3]));
            act1[(((size_t)bb * 6 + oc) * 254 + py) * 254 + px] = sigmf(m);
        }
    }
}

// ---------------- conv2 + sigmoid + maxpool ----------------
__global__ __launch_bounds__(256) void k_conv2(const float* __restrict__ act1,
                                               const float* __restrict__ w,
                                               const float* __restrict__ bias,
                                               float* __restrict__ act2) {
    __shared__ float sIn[6][36][37];
    __shared__ float sW[8][6][25];
    __shared__ float sB[8];
    const int bx = blockIdx.x, by = blockIdx.y;
    const int bb = blockIdx.z >> 1, og = (blockIdx.z & 1) * 8;
    const int tx = threadIdx.x, ty = threadIdx.y;
    const int tid = ty * 16 + tx;

    for (int i = tid; i < 8 * 6 * 25; i += 256) {
        int oc = i / 150, r = i % 150, ic = r / 25, k = r % 25;
        sW[oc][ic][k] = w[((og + oc) * 6 + ic) * 25 + k];
    }
    if (tid < 8) sB[tid] = bias[og + tid];

    const int iy0 = by * 32, ix0 = bx * 32;
    for (int ic = 0; ic < 6; ++ic) {
        const float* ip = act1 + ((size_t)bb * 6 + ic) * 254 * 254;
        for (int i = tid; i < 36 * 36; i += 256) {
            int r = i / 36, c = i % 36;
            int gy = iy0 + r, gx = ix0 + c;
            sIn[ic][r][c] = (gy < 254 && gx < 254) ? ip[gy * 254 + gx] : 0.0f;
        }
    }
    __syncthreads();

    float acc[8][4];
#pragma unroll
    for (int oc = 0; oc < 8; ++oc) {
        float bv = sB[oc];
        acc[oc][0] = bv; acc[oc][1] = bv; acc[oc][2] = bv; acc[oc][3] = bv;
    }

    for (int ic = 0; ic < 6; ++ic) {
        float win[6][6];
#pragma unroll
        for (int r = 0; r < 6; ++r)
#pragma unroll
            for (int c = 0; c < 6; ++c) win[r][c] = sIn[ic][2 * ty + r][2 * tx + c];
#pragma unroll
        for (int oc = 0; oc < 8; ++oc)
#pragma unroll
            for (int ky = 0; ky < 5; ++ky)
#pragma unroll
                for (int kx = 0; kx < 5; ++kx) {
                    float wv = sW[oc][ic][ky * 5 + kx];
                    acc[oc][0] = fmaf(wv, win[ky][kx], acc[oc][0]);
                    acc[oc][1] = fmaf(wv, win[ky][kx + 1], acc[oc][1]);
                    acc[oc][2] = fmaf(wv, win[ky + 1][kx], acc[oc][2]);
                    acc[oc][3] = fmaf(wv, win[ky + 1][kx + 1], acc[oc][3]);
                }
    }

    const int py = by * 16 + ty, px = bx * 16 + tx;
    if (py < 125 && px < 125) {
#pragma unroll
        for (int oc = 0; oc < 8; ++oc) {
            float m = fmaxf(fmaxf(acc[oc][0], acc[oc][1]), fmaxf(acc[oc][2], acc[oc][3]));
            act2[(((size_t)bb * 16 + og + oc) * 125 + py) * 125 + px] = sigmf(m);
        }
    }
}

// ---------------- fc0 partials (latency-optimized, o-split + unroll) -------
// X = act2 flat (16,250000); W = fc0_w (120,250000). y[b][o] = sum_k X W.
// grid (489, 2): x = k-block (512 k), y = o-half (60 outputs).
// Block = 4 waves; wave k-span 128. Lane l: s = l&7 (k-slice), b2 = l>>3
// (batch pair). Per o: 4 coalesced float4 W loads, 32 FMA, 6 shfl.
// o-loop unrolled 4x -> 16 loads + 8 independent FMA chains in flight.
#define FC0_KBLK 512
#define FC0_NB   489  // ceil(250000/512); 488*512=249856, tail 144

__global__ __launch_bounds__(256) void k_fc0(const float* __restrict__ x,
                                             const float* __restrict__ w,
                                             float* __restrict__ partial) {
    __shared__ float sY[4][60][16];
    const int tid = threadIdx.x;
    const int wv = tid >> 6, l = tid & 63;
    const int s = l & 7, b2 = l >> 3;
    const int kw = blockIdx.x * FC0_KBLK + wv * 128;  // wave k-base
    const int o0 = blockIdx.y * 60;                    // o-half base

    int koff[4];
    bool inb[4];
#pragma unroll
    for (int j = 0; j < 4; ++j) {
        int kj = kw + j * 32 + s * 4;
        inb[j] = (kj < 250000);
        koff[j] = inb[j] ? kj : 249996;
    }

    const int b0i = b2 * 2;
    float4 xr[2][4];
#pragma unroll
    for (int bi = 0; bi < 2; ++bi) {
        const float* xp = x + (size_t)(b0i + bi) * 250000;
#pragma unroll
        for (int j = 0; j < 4; ++j) {
            if (inb[j]) xr[bi][j] = *(const float4*)(xp + koff[j]);
            else xr[bi][j] = make_float4(0.f, 0.f, 0.f, 0.f);
        }
    }

#pragma unroll 4
    for (int ol = 0; ol < 60; ++ol) {
        const float* row = w + (size_t)(o0 + ol) * 250000;
        float a0 = 0.0f, a1 = 0.0f;
#pragma unroll
        for (int j = 0; j < 4; ++j) {
            float4 w4 = *(const float4*)(row + koff[j]);
            a0 = fmaf(xr[0][j].x, w4.x, a0);
            a0 = fmaf(xr[0][j].y, w4.y, a0);
            a0 = fmaf(xr[0][j].z, w4.z, a0);
            a0 = fmaf(xr[0][j].w, w4.w, a0);
            a1 = fmaf(xr[1][j].x, w4.x, a1);
            a1 = fmaf(xr[1][j].y, w4.y, a1);
            a1 = fmaf(xr[1][j].z, w4.z, a1);
            a1 = fmaf(xr[1][j].w, w4.w, a1);
        }
        a0 += __shfl_xor(a0, 1); a1 += __shfl_xor(a1, 1);
        a0 += __shfl_xor(a0, 2); a1 += __shfl_xor(a1, 2);
        a0 += __shfl_xor(a0, 4); a1 += __shfl_xor(a1, 4);
        if (s == 0) {
            sY[wv][ol][b0i] = a0;
            sY[wv][ol][b0i + 1] = a1;
        }
    }
    __syncthreads();

    // cross-wave reduce -> partial[blk][(o0+ol)*16+b]
    float* pp = partial + (size_t)blockIdx.x * 1920;
    for (int i = tid; i < 960; i += 256) {
        int ol = i >> 4, b = i & 15;
        float v = sY[0][ol][b] + sY[1][ol][b] + sY[2][ol][b] + sY[3][ol][b];
        pp[(o0 + ol) * 16 + b] = v;
    }
}

// ---------------- fc0 reduce + bias + sigmoid ----------------
// partial layout: [489][o*16+b]. One wave per (o,b); h0[b*120+o].
__global__ __launch_bounds__(256) void k_fc0red(const float* __restrict__ partial,
                                                const float* __restrict__ b0,
                                                float* __restrict__ h0) {
    const int tid = threadIdx.x;
    const int wv = tid >> 6, l = tid & 63;
    const int i = blockIdx.x * 4 + wv;  // 0..1919 = o*16+b
    float s = 0.0f;
    for (int c = l; c < FC0_NB; c += 64) s += partial[(size_t)c * 1920 + i];
    s += __shfl_xor(s, 1);
    s += __shfl_xor(s, 2);
    s += __shfl_xor(s, 4);
    s += __shfl_xor(s, 8);
    s += __shfl_xor(s, 16);
    s += __shfl_xor(s, 32);
    if (l == 0) {
        int o = i >> 4, b = i & 15;
        h0[b * 120 + o] = sigmf(s + b0[o]);
    }
}

// ---------------- fc1 + fc2 + gamma/gain params ----------------
__global__ __launch_bounds__(256) void k_fctail(const float* __restrict__ h0in,
                                                const float* __restrict__ fc1_w,
                                                const float* __restrict__ fc1_b,
                                                const float* __restrict__ fc2_w,
                                                const float* __restrict__ fc2_b,
                                                const float* __restrict__ gb1,
                                                const float* __restrict__ gb2,
                                                const float* __restrict__ base1,
                                                float* __restrict__ params) {
    __shared__ float sh0[1920];
    __shared__ float sh1[16][84];
    __shared__ float sout[16][10];
    const int tid = threadIdx.x;

    for (int i = tid; i < 1920; i += 256) sh0[i] = h0in[i];
    __syncthreads();

    for (int i = tid; i < 16 * 84; i += 256) {
        int b = i / 84, o = i % 84;
        float a = fc1_b[o];
        for (int k = 0; k < 120; ++k) a = fmaf(sh0[b * 120 + k], fc1_w[o * 120 + k], a);
        sh1[b][o] = sigmf(a);
    }
    __syncthreads();

    for (int i = tid; i < 160; i += 256) {
        int b = i / 10, o = i % 10;
        float a = fc2_b[o];
        for (int k = 0; k < 84; ++k) a = fmaf(sh1[b][k], fc2_w[o * 84 + k], a);
        sout[b][o] = a;
    }
    __syncthreads();

    if (tid < 16) {
        int b = tid;
        float g1 = sout[b][0] + gb1[0];
        float g2 = sout[b][1] + gb2[0];
        float gain = 0.0f;
        for (int j = 0; j < 8; ++j) gain += sout[b][2 + j] + base1[j];
        params[b] = g1;
        params[16 + b] = g2;
        params[32 + b] = gain;
    }
}

// ---------------- final: mask + clip + pow (float4) ----------------
__global__ __launch_bounds__(256) void k_final(const float* __restrict__ img,
                                               const float* __restrict__ params,
                                               float* __restrict__ out) {
    int idx = blockIdx.x * 256 + threadIdx.x;  // group of 4 pixels
    int p = idx * 4;
    int b = p >> 18;
    int hw = p & 262143;
    size_t base = ((size_t)b * 3) * 262144 + hw;

    float4 r = *(const float4*)(img + base);
    float4 g = *(const float4*)(img + base + 262144);
    float4 bl = *(const float4*)(img + base + 2 * 262144);
    float g1 = params[b], g2 = params[16 + b], gain = params[32 + b];

    float4 o0, o1, o2;
#pragma unroll
    for (int e = 0; e < 4; ++e) {
        float re = (&r.x)[e], ge = (&g.x)[e], be = (&bl.x)[e];
        float I = (re + ge + be) * (1.0f / 3.0f);
        float gv = (I > 0.5f) ? g2 : g1;
        (&o0.x)[e] = __powf(fminf(fmaxf(re * gain, EPSF), 1.0f), gv);
        (&o1.x)[e] = __powf(fminf(fmaxf(ge * gain, EPSF), 1.0f), gv);
        (&o2.x)[e] = __powf(fminf(fmaxf(be * gain, EPSF), 1.0f), gv);
    }
    *(float4*)(out + base) = o0;
    *(float4*)(out + base + 262144) = o1;
    *(float4*)(out + base + 2 * 262144) = o2;
}

// ---------------------------------------------------------------------------
extern "C" void kernel_launch(void* const* d_in, const int* in_sizes, int n_in,
                              void* d_out, int out_size, void* d_ws, size_t ws_size,
                              hipStream_t stream) {
    const float* img     = (const float*)d_in[0];
    const float* conv1_w = (const float*)d_in[1];
    const float* conv1_b = (const float*)d_in[2];
    const float* conv2_w = (const float*)d_in[3];
    const float* conv2_b = (const float*)d_in[4];
    const float* fc0_w   = (const float*)d_in[5];
    const float* fc0_b   = (const float*)d_in[6];
    const float* fc1_w   = (const float*)d_in[7];
    const float* fc1_b   = (const float*)d_in[8];
    const float* fc2_w   = (const float*)d_in[9];
    const float* fc2_b   = (const float*)d_in[10];
    const float* gb1     = (const float*)d_in[11];
    const float* gb2     = (const float*)d_in[12];
    const float* base1   = (const float*)d_in[13];

    float* outp = (float*)d_out;
    float* act1    = outp;                      // 6,193,536
    float* act2    = outp + 6193536;            // 4,000,000
    float* partial = outp + 10193536;           // 489*1920 = 938,880
    float* h0      = outp + 11132416;           // 1,920
    float* params  = (float*)d_ws;              // 48 floats

    k_conv1<<<dim3(16, 16, 16), dim3(16, 16), 0, stream>>>(img, conv1_w, conv1_b, act1);
    k_conv2<<<dim3(8, 8, 32), dim3(16, 16), 0, stream>>>(act1, conv2_w, conv2_b, act2);
    k_fc0<<<dim3(FC0_NB, 2), dim3(256), 0, stream>>>(act2, fc0_w, partial);
    k_fc0red<<<dim3(480), dim3(256), 0, stream>>>(partial, fc0_b, h0);
    k_fctail<<<dim3(1), dim3(256), 0, stream>>>(h0, fc1_w, fc1_b, fc2_w, fc2_b,
                                                gb1, gb2, base1, params);
    k_final<<<dim3(4096), dim3(256), 0, stream>>>(img, params, outp);
}

// Round 4
// 236.854 us; speedup vs baseline: 1.4516x; 1.1824x over previous
//
#include <hip/hip_runtime.h>
#include <hip/hip_bf16.h>
#include <math.h>

// ---------------------------------------------------------------------------
// LeNet-ish forward, MFMA convs. Scratch inside d_out (float units):
//  [0)          act1 (bf16)  6,193,536 u16 = 3,096,768 f
//  [3,096,768)  act2 (f32)   4,000,000
//  [7,096,768)  fc0 partials 489*1920 = 938,880
//  [8,035,648)  h0           1,920
// d_ws: params g1[16], g2[16], gain[16]
// ---------------------------------------------------------------------------

#define EPSF 1e-8f
typedef unsigned short ushort_t;
typedef __attribute__((ext_vector_type(8))) short short8;
typedef __attribute__((ext_vector_type(4))) float f32x4;

__device__ __forceinline__ float sigmf(float x) {
    return 1.0f / (1.0f + __expf(-x));
}
__device__ __forceinline__ unsigned short f2bf(float f) {
    unsigned int u = __float_as_uint(f);
    unsigned int r = (u + 0x7FFFu + ((u >> 16) & 1u)) >> 16;
    return (unsigned short)r;
}
__device__ __forceinline__ float bf2f(unsigned short h) {
    unsigned int u = ((unsigned int)h) << 16;
    return __uint_as_float(u);
}

// ============================ conv1 (MFMA) =================================
// img (16,3,512,512) f32 -> act1 (16,6,254,254) bf16 (sigmoid(maxpool(conv)))
// Block: (xc 0..3, yc 0..63, b). Covers pooled rows 4yc..4yc+3, x chunk 128.
// LDS: 2 phase copies of [3 planes x 12 rows + 8 zero rows] x 144 bf16.
#define C1_W     144
#define C1_ROWB  288           // W*2 bytes
#define C1_NR    12
#define C1_ZROW  36
#define C1_ROWS  44
#define C1_PH    (C1_ROWS * C1_ROWB)   // 12672

__global__ __launch_bounds__(256) void k_conv1(const float* __restrict__ img,
                                               const float* __restrict__ w,
                                               const float* __restrict__ bias,
                                               ushort_t* __restrict__ act1) {
    __shared__ unsigned char sh[2 * C1_PH];
    const int tid = threadIdx.x;
    const int xc = blockIdx.x, yc = blockIdx.y, b = blockIdx.z;
    const int x0c = xc * 128;

    // zero rows (both phases)
    for (int i = tid; i < 2 * 8 * 72; i += 256) {
        int ph = i / (8 * 72);
        int rr = (i / 72) % 8;
        int cc = i % 72;
        *(unsigned int*)(sh + ph * C1_PH + (C1_ZROW + rr) * C1_ROWB + cc * 4) = 0u;
    }
    // data rows, phase 0/1 (phase p stores value at global x = x0c + idx + p)
    for (int ph = 0; ph < 2; ++ph) {
        for (int i = tid; i < 3 * C1_NR * 72; i += 256) {
            int plane = i / (C1_NR * 72);
            int rr = (i / 72) % C1_NR;
            int cc = (i % 72) * 2;
            int gr = 8 * yc + rr;
            int gx = x0c + cc + ph;
            const float* ip = img + ((size_t)(b * 3 + plane) * 512 + gr) * 512;
            float v0 = (gr < 512 && gx < 512) ? ip[gx] : 0.f;
            float v1 = (gr < 512 && gx + 1 < 512) ? ip[gx + 1] : 0.f;
            unsigned int pk = (unsigned int)f2bf(v0) | ((unsigned int)f2bf(v1) << 16);
            *(unsigned int*)(sh + ph * C1_PH + (plane * C1_NR + rr) * C1_ROWB + cc * 2) = pk;
        }
    }

    const int lane = tid & 63;
    const int g = lane >> 4;
    const int m = lane & 15;

    // B fragments: taps t=4s+g, t<15 real; fold gray channel (w3/3) into rgb.
    const int ocw = (m < 6) ? m : 0;
    short8 fb[4];
#pragma unroll
    for (int s = 0; s < 4; ++s) {
        int t = 4 * s + g;
        unsigned int u0 = 0, u1 = 0, u2 = 0;
        if (t < 15 && m < 6) {
            int ic = t / 5, ky = t % 5;
            const float* wp = w + ((ocw * 4 + ic) * 5 + ky) * 5;
            const float* w3 = w + ((ocw * 4 + 3) * 5 + ky) * 5;
            float v0 = wp[0] + w3[0] * (1.f / 3.f);
            float v1 = wp[1] + w3[1] * (1.f / 3.f);
            float v2 = wp[2] + w3[2] * (1.f / 3.f);
            float v3 = wp[3] + w3[3] * (1.f / 3.f);
            float v4 = wp[4] + w3[4] * (1.f / 3.f);
            u0 = (unsigned int)f2bf(v0) | ((unsigned int)f2bf(v1) << 16);
            u1 = (unsigned int)f2bf(v2) | ((unsigned int)f2bf(v3) << 16);
            u2 = (unsigned int)f2bf(v4);
        }
        union { unsigned int u[4]; short8 v; } uu;
        uu.u[0] = u0; uu.u[1] = u1; uu.u[2] = u2; uu.u[3] = 0;
        fb[s] = uu.v;
    }
    unsigned int offv[4];
#pragma unroll
    for (int s = 0; s < 4; ++s) {
        int t = 4 * s + g;
        offv[s] = (t < 15) ? (unsigned int)(((t / 5) * C1_NR + (t % 5)) * C1_ROWB)
                           : (unsigned int)(C1_ZROW * C1_ROWB);
    }
    const float bv = (m < 6) ? bias[m] : 0.f;
    __syncthreads();

    const int wv = tid >> 6;
    const int par = m & 1;
    const int mh = m >> 1;
    for (int it = wv; it < 64; it += 4) {
        int rp = it >> 4, xt = it & 15;
        int x0 = x0c + xt * 8;
        int xcol = x0 + mh;
        int phi = xcol & 1;
        int i0 = (xcol - x0c) & ~1;
        const unsigned char* base = sh + phi * C1_PH + (2 * rp + par) * C1_ROWB + i0 * 2;
        f32x4 acc = {0.f, 0.f, 0.f, 0.f};
#pragma unroll
        for (int s = 0; s < 4; ++s) {
            const unsigned int* p = (const unsigned int*)(base + offv[s]);
            union { unsigned int u[4]; short8 v; } ua;
            ua.u[0] = p[0];
            ua.u[1] = p[1];
            ua.u[2] = p[2] & 0xFFFFu;
            ua.u[3] = 0;
            acc = __builtin_amdgcn_mfma_f32_16x16x32_bf16(ua.v, fb[s], acc, 0, 0, 0);
        }
        int YP = 4 * yc + rp;
        int xp = (x0 >> 1) + g;
        if (m < 6 && YP < 254 && (x0 + 2 * g + 1) < 508) {
            float mx = fmaxf(fmaxf(acc[0], acc[1]), fmaxf(acc[2], acc[3])) + bv;
            act1[((size_t)(b * 6 + m) * 254 + YP) * 254 + xp] = f2bf(sigmf(mx));
        }
    }
}

// ============================ conv2 (MFMA) =================================
// act1 (16,6,254,254) bf16 -> act2 (16,16,125,125) f32
// Block: (xc 0..1, yc 0..62, b). Covers pooled rows 2yc..2yc+1, x chunk 128.
#define C2_W     144
#define C2_ROWB  288
#define C2_NR    8
#define C2_ZROW  48
#define C2_ROWS  52
#define C2_PH    (C2_ROWS * C2_ROWB)   // 14976

__global__ __launch_bounds__(256) void k_conv2(const ushort_t* __restrict__ act1,
                                               const float* __restrict__ w,
                                               const float* __restrict__ bias,
                                               float* __restrict__ act2) {
    __shared__ unsigned char sh[2 * C2_PH];
    const int tid = threadIdx.x;
    const int xc = blockIdx.x, yc = blockIdx.y, b = blockIdx.z;
    const int x0c = xc * 128;

    for (int i = tid; i < 2 * 4 * 72; i += 256) {
        int ph = i / (4 * 72);
        int rr = (i / 72) % 4;
        int cc = i % 72;
        *(unsigned int*)(sh + ph * C2_PH + (C2_ZROW + rr) * C2_ROWB + cc * 4) = 0u;
    }
    for (int ph = 0; ph < 2; ++ph) {
        for (int i = tid; i < 6 * C2_NR * 72; i += 256) {
            int plane = i / (C2_NR * 72);
            int rr = (i / 72) % C2_NR;
            int cc = (i % 72) * 2;
            int gr = 4 * yc + rr;
            int gx = x0c + cc + ph;
            const ushort_t* ip = act1 + ((size_t)(b * 6 + plane) * 254 + gr) * 254;
            unsigned int h0 = (gr < 254 && gx < 254) ? ip[gx] : 0;
            unsigned int h1 = (gr < 254 && gx + 1 < 254) ? ip[gx + 1] : 0;
            *(unsigned int*)(sh + ph * C2_PH + (plane * C2_NR + rr) * C2_ROWB + cc * 2) =
                h0 | (h1 << 16);
        }
    }

    const int lane = tid & 63;
    const int g = lane >> 4;
    const int m = lane & 15;   // = oc for B/D cols

    short8 fb[8];
#pragma unroll
    for (int s = 0; s < 8; ++s) {
        int t = 4 * s + g;
        unsigned int u0 = 0, u1 = 0, u2 = 0;
        if (t < 30) {
            int ic = t / 5, ky = t % 5;
            const float* wp = w + ((m * 6 + ic) * 5 + ky) * 5;
            u0 = (unsigned int)f2bf(wp[0]) | ((unsigned int)f2bf(wp[1]) << 16);
            u1 = (unsigned int)f2bf(wp[2]) | ((unsigned int)f2bf(wp[3]) << 16);
            u2 = (unsigned int)f2bf(wp[4]);
        }
        union { unsigned int u[4]; short8 v; } uu;
        uu.u[0] = u0; uu.u[1] = u1; uu.u[2] = u2; uu.u[3] = 0;
        fb[s] = uu.v;
    }
    unsigned int offv[8];
#pragma unroll
    for (int s = 0; s < 8; ++s) {
        int t = 4 * s + g;
        offv[s] = (t < 30) ? (unsigned int)(((t / 5) * C2_NR + (t % 5)) * C2_ROWB)
                           : (unsigned int)(C2_ZROW * C2_ROWB);
    }
    const float bv = bias[m];
    __syncthreads();

    const int wv = tid >> 6;
    const int par = m & 1;
    const int mh = m >> 1;
    for (int it = wv; it < 32; it += 4) {
        int rp = it >> 4, xt = it & 15;
        int x0 = x0c + xt * 8;
        int xcol = x0 + mh;
        int phi = xcol & 1;
        int i0 = (xcol - x0c) & ~1;
        const unsigned char* base = sh + phi * C2_PH + (2 * rp + par) * C2_ROWB + i0 * 2;
        f32x4 acc = {0.f, 0.f, 0.f, 0.f};
#pragma unroll
        for (int s = 0; s < 8; ++s) {
            const unsigned int* p = (const unsigned int*)(base + offv[s]);
            union { unsigned int u[4]; short8 v; } ua;
            ua.u[0] = p[0];
            ua.u[1] = p[1];
            ua.u[2] = p[2] & 0xFFFFu;
            ua.u[3] = 0;
            acc = __builtin_amdgcn_mfma_f32_16x16x32_bf16(ua.v, fb[s], acc, 0, 0, 0);
        }
        int YP = 2 * yc + rp;
        int xp = (x0 >> 1) + g;
        if (YP < 125 && (x0 + 2 * g + 1) < 250) {
            float mx = fmaxf(fmaxf(acc[0], acc[1]), fmaxf(acc[2], acc[3])) + bv;
            act2[((size_t)(b * 16 + m) * 125 + YP) * 125 + xp] = sigmf(mx);
        }
    }
}

// ---------------- fc0 partials (unchanged from R3) ----------------
#define FC0_KBLK 512
#define FC0_NB   489

__global__ __launch_bounds__(256) void k_fc0(const float* __restrict__ x,
                                             const float* __restrict__ w,
                                             float* __restrict__ partial) {
    __shared__ float sY[4][60][16];
    const int tid = threadIdx.x;
    const int wv = tid >> 6, l = tid & 63;
    const int s = l & 7, b2 = l >> 3;
    const int kw = blockIdx.x * FC0_KBLK + wv * 128;
    const int o0 = blockIdx.y * 60;

    int koff[4];
    bool inb[4];
#pragma unroll
    for (int j = 0; j < 4; ++j) {
        int kj = kw + j * 32 + s * 4;
        inb[j] = (kj < 250000);
        koff[j] = inb[j] ? kj : 249996;
    }

    const int b0i = b2 * 2;
    float4 xr[2][4];
#pragma unroll
    for (int bi = 0; bi < 2; ++bi) {
        const float* xp = x + (size_t)(b0i + bi) * 250000;
#pragma unroll
        for (int j = 0; j < 4; ++j) {
            if (inb[j]) xr[bi][j] = *(const float4*)(xp + koff[j]);
            else xr[bi][j] = make_float4(0.f, 0.f, 0.f, 0.f);
        }
    }

#pragma unroll 4
    for (int ol = 0; ol < 60; ++ol) {
        const float* row = w + (size_t)(o0 + ol) * 250000;
        float a0 = 0.0f, a1 = 0.0f;
#pragma unroll
        for (int j = 0; j < 4; ++j) {
            float4 w4 = *(const float4*)(row + koff[j]);
            a0 = fmaf(xr[0][j].x, w4.x, a0);
            a0 = fmaf(xr[0][j].y, w4.y, a0);
            a0 = fmaf(xr[0][j].z, w4.z, a0);
            a0 = fmaf(xr[0][j].w, w4.w, a0);
            a1 = fmaf(xr[1][j].x, w4.x, a1);
            a1 = fmaf(xr[1][j].y, w4.y, a1);
            a1 = fmaf(xr[1][j].z, w4.z, a1);
            a1 = fmaf(xr[1][j].w, w4.w, a1);
        }
        a0 += __shfl_xor(a0, 1); a1 += __shfl_xor(a1, 1);
        a0 += __shfl_xor(a0, 2); a1 += __shfl_xor(a1, 2);
        a0 += __shfl_xor(a0, 4); a1 += __shfl_xor(a1, 4);
        if (s == 0) {
            sY[wv][ol][b0i] = a0;
            sY[wv][ol][b0i + 1] = a1;
        }
    }
    __syncthreads();

    float* pp = partial + (size_t)blockIdx.x * 1920;
    for (int i = tid; i < 960; i += 256) {
        int ol = i >> 4, bb = i & 15;
        float v = sY[0][ol][bb] + sY[1][ol][bb] + sY[2][ol][bb] + sY[3][ol][bb];
        pp[(o0 + ol) * 16 + bb] = v;
    }
}

__global__ __launch_bounds__(256) void k_fc0red(const float* __restrict__ partial,
                                                const float* __restrict__ b0,
                                                float* __restrict__ h0) {
    const int tid = threadIdx.x;
    const int wv = tid >> 6, l = tid & 63;
    const int i = blockIdx.x * 4 + wv;
    float s = 0.0f;
    for (int c = l; c < FC0_NB; c += 64) s += partial[(size_t)c * 1920 + i];
    s += __shfl_xor(s, 1);
    s += __shfl_xor(s, 2);
    s += __shfl_xor(s, 4);
    s += __shfl_xor(s, 8);
    s += __shfl_xor(s, 16);
    s += __shfl_xor(s, 32);
    if (l == 0) {
        int o = i >> 4, bb = i & 15;
        h0[bb * 120 + o] = sigmf(s + b0[o]);
    }
}

__global__ __launch_bounds__(256) void k_fctail(const float* __restrict__ h0in,
                                                const float* __restrict__ fc1_w,
                                                const float* __restrict__ fc1_b,
                                                const float* __restrict__ fc2_w,
                                                const float* __restrict__ fc2_b,
                                                const float* __restrict__ gb1,
                                                const float* __restrict__ gb2,
                                                const float* __restrict__ base1,
                                                float* __restrict__ params) {
    __shared__ float sh0[1920];
    __shared__ float sh1[16][84];
    __shared__ float sout[16][10];
    const int tid = threadIdx.x;

    for (int i = tid; i < 1920; i += 256) sh0[i] = h0in[i];
    __syncthreads();

    for (int i = tid; i < 16 * 84; i += 256) {
        int bb = i / 84, o = i % 84;
        float a = fc1_b[o];
        for (int k = 0; k < 120; ++k) a = fmaf(sh0[bb * 120 + k], fc1_w[o * 120 + k], a);
        sh1[bb][o] = sigmf(a);
    }
    __syncthreads();

    for (int i = tid; i < 160; i += 256) {
        int bb = i / 10, o = i % 10;
        float a = fc2_b[o];
        for (int k = 0; k < 84; ++k) a = fmaf(sh1[bb][k], fc2_w[o * 84 + k], a);
        sout[bb][o] = a;
    }
    __syncthreads();

    if (tid < 16) {
        int bb = tid;
        float g1 = sout[bb][0] + gb1[0];
        float g2 = sout[bb][1] + gb2[0];
        float gain = 0.0f;
        for (int j = 0; j < 8; ++j) gain += sout[bb][2 + j] + base1[j];
        params[bb] = g1;
        params[16 + bb] = g2;
        params[32 + bb] = gain;
    }
}

__global__ __launch_bounds__(256) void k_final(const float* __restrict__ img,
                                               const float* __restrict__ params,
                                               float* __restrict__ out) {
    int idx = blockIdx.x * 256 + threadIdx.x;
    int p = idx * 4;
    int b = p >> 18;
    int hw = p & 262143;
    size_t base = ((size_t)b * 3) * 262144 + hw;

    float4 r = *(const float4*)(img + base);
    float4 g = *(const float4*)(img + base + 262144);
    float4 bl = *(const float4*)(img + base + 2 * 262144);
    float g1 = params[b], g2 = params[16 + b], gain = params[32 + b];

    float4 o0, o1, o2;
#pragma unroll
    for (int e = 0; e < 4; ++e) {
        float re = (&r.x)[e], ge = (&g.x)[e], be = (&bl.x)[e];
        float I = (re + ge + be) * (1.0f / 3.0f);
        float gv = (I > 0.5f) ? g2 : g1;
        (&o0.x)[e] = __powf(fminf(fmaxf(re * gain, EPSF), 1.0f), gv);
        (&o1.x)[e] = __powf(fminf(fmaxf(ge * gain, EPSF), 1.0f), gv);
        (&o2.x)[e] = __powf(fminf(fmaxf(be * gain, EPSF), 1.0f), gv);
    }
    *(float4*)(out + base) = o0;
    *(float4*)(out + base + 262144) = o1;
    *(float4*)(out + base + 2 * 262144) = o2;
}

// ---------------------------------------------------------------------------
extern "C" void kernel_launch(void* const* d_in, const int* in_sizes, int n_in,
                              void* d_out, int out_size, void* d_ws, size_t ws_size,
                              hipStream_t stream) {
    const float* img     = (const float*)d_in[0];
    const float* conv1_w = (const float*)d_in[1];
    const float* conv1_b = (const float*)d_in[2];
    const float* conv2_w = (const float*)d_in[3];
    const float* conv2_b = (const float*)d_in[4];
    const float* fc0_w   = (const float*)d_in[5];
    const float* fc0_b   = (const float*)d_in[6];
    const float* fc1_w   = (const float*)d_in[7];
    const float* fc1_b   = (const float*)d_in[8];
    const float* fc2_w   = (const float*)d_in[9];
    const float* fc2_b   = (const float*)d_in[10];
    const float* gb1     = (const float*)d_in[11];
    const float* gb2     = (const float*)d_in[12];
    const float* base1   = (const float*)d_in[13];

    float* outp = (float*)d_out;
    ushort_t* act1 = (ushort_t*)outp;           // 6,193,536 bf16
    float* act2    = outp + 3096768;            // 4,000,000 f32
    float* partial = outp + 7096768;            // 938,880
    float* h0      = outp + 8035648;            // 1,920
    float* params  = (float*)d_ws;              // 48 floats

    k_conv1<<<dim3(4, 64, 16), dim3(256), 0, stream>>>(img, conv1_w, conv1_b, act1);
    k_conv2<<<dim3(2, 63, 16), dim3(256), 0, stream>>>(act1, conv2_w, conv2_b, act2);
    k_fc0<<<dim3(FC0_NB, 2), dim3(256), 0, stream>>>(act2, fc0_w, partial);
    k_fc0red<<<dim3(480), dim3(256), 0, stream>>>(partial, fc0_b, h0);
    k_fctail<<<dim3(1), dim3(256), 0, stream>>>(h0, fc1_w, fc1_b, fc2_w, fc2_b,
                                                gb1, gb2, base1, params);
    k_final<<<dim3(4096), dim3(256), 0, stream>>>(img, params, outp);
}

// Round 5
// 227.089 us; speedup vs baseline: 1.5140x; 1.0430x over previous
//
#include <hip/hip_runtime.h>
#include <hip/hip_bf16.h>
#include <math.h>

// ---------------------------------------------------------------------------
// LeNet-ish forward, MFMA convs. Scratch inside d_out (float units):
//  [0)          act1 (bf16)  6,193,536 u16 = 3,096,768 f
//  [3,096,768)  act2 (f32)   4,000,000
//  [7,096,768)  fc0 partials 489*1920 = 938,880
//  [8,035,648)  h0           1,920
// d_ws: params g1[16], g2[16], gain[16]
// ---------------------------------------------------------------------------

#define EPSF 1e-8f
typedef unsigned short ushort_t;
typedef __attribute__((ext_vector_type(8))) short short8;
typedef __attribute__((ext_vector_type(4))) float f32x4;

__device__ __forceinline__ float sigmf(float x) {
    return 1.0f / (1.0f + __expf(-x));
}
__device__ __forceinline__ unsigned short f2bf(float f) {
    unsigned int u = __float_as_uint(f);
    unsigned int r = (u + 0x7FFFu + ((u >> 16) & 1u)) >> 16;
    return (unsigned short)r;
}

// ============================ conv1 (MFMA) =================================
#define C1_W     144
#define C1_ROWB  288
#define C1_NR    12
#define C1_ZROW  36
#define C1_ROWS  44
#define C1_PH    (C1_ROWS * C1_ROWB)

__global__ __launch_bounds__(256) void k_conv1(const float* __restrict__ img,
                                               const float* __restrict__ w,
                                               const float* __restrict__ bias,
                                               ushort_t* __restrict__ act1) {
    __shared__ unsigned char sh[2 * C1_PH];
    const int tid = threadIdx.x;
    const int xc = blockIdx.x, yc = blockIdx.y, b = blockIdx.z;
    const int x0c = xc * 128;

    for (int i = tid; i < 2 * 8 * 72; i += 256) {
        int ph = i / (8 * 72);
        int rr = (i / 72) % 8;
        int cc = i % 72;
        *(unsigned int*)(sh + ph * C1_PH + (C1_ZROW + rr) * C1_ROWB + cc * 4) = 0u;
    }
    for (int ph = 0; ph < 2; ++ph) {
        for (int i = tid; i < 3 * C1_NR * 72; i += 256) {
            int plane = i / (C1_NR * 72);
            int rr = (i / 72) % C1_NR;
            int cc = (i % 72) * 2;
            int gr = 8 * yc + rr;
            int gx = x0c + cc + ph;
            const float* ip = img + ((size_t)(b * 3 + plane) * 512 + gr) * 512;
            float v0 = (gr < 512 && gx < 512) ? ip[gx] : 0.f;
            float v1 = (gr < 512 && gx + 1 < 512) ? ip[gx + 1] : 0.f;
            unsigned int pk = (unsigned int)f2bf(v0) | ((unsigned int)f2bf(v1) << 16);
            *(unsigned int*)(sh + ph * C1_PH + (plane * C1_NR + rr) * C1_ROWB + cc * 2) = pk;
        }
    }

    const int lane = tid & 63;
    const int g = lane >> 4;
    const int m = lane & 15;

    const int ocw = (m < 6) ? m : 0;
    short8 fb[4];
#pragma unroll
    for (int s = 0; s < 4; ++s) {
        int t = 4 * s + g;
        unsigned int u0 = 0, u1 = 0, u2 = 0;
        if (t < 15 && m < 6) {
            int ic = t / 5, ky = t % 5;
            const float* wp = w + ((ocw * 4 + ic) * 5 + ky) * 5;
            const float* w3 = w + ((ocw * 4 + 3) * 5 + ky) * 5;
            float v0 = wp[0] + w3[0] * (1.f / 3.f);
            float v1 = wp[1] + w3[1] * (1.f / 3.f);
            float v2 = wp[2] + w3[2] * (1.f / 3.f);
            float v3 = wp[3] + w3[3] * (1.f / 3.f);
            float v4 = wp[4] + w3[4] * (1.f / 3.f);
            u0 = (unsigned int)f2bf(v0) | ((unsigned int)f2bf(v1) << 16);
            u1 = (unsigned int)f2bf(v2) | ((unsigned int)f2bf(v3) << 16);
            u2 = (unsigned int)f2bf(v4);
        }
        union { unsigned int u[4]; short8 v; } uu;
        uu.u[0] = u0; uu.u[1] = u1; uu.u[2] = u2; uu.u[3] = 0;
        fb[s] = uu.v;
    }
    unsigned int offv[4];
#pragma unroll
    for (int s = 0; s < 4; ++s) {
        int t = 4 * s + g;
        offv[s] = (t < 15) ? (unsigned int)(((t / 5) * C1_NR + (t % 5)) * C1_ROWB)
                           : (unsigned int)(C1_ZROW * C1_ROWB);
    }
    const float bv = (m < 6) ? bias[m] : 0.f;
    __syncthreads();

    const int wv = tid >> 6;
    const int par = m & 1;
    const int mh = m >> 1;
    for (int it = wv; it < 64; it += 4) {
        int rp = it >> 4, xt = it & 15;
        int x0 = x0c + xt * 8;
        int xcol = x0 + mh;
        int phi = xcol & 1;
        int i0 = (xcol - x0c) & ~1;
        const unsigned char* base = sh + phi * C1_PH + (2 * rp + par) * C1_ROWB + i0 * 2;
        f32x4 acc = {0.f, 0.f, 0.f, 0.f};
#pragma unroll
        for (int s = 0; s < 4; ++s) {
            const unsigned int* p = (const unsigned int*)(base + offv[s]);
            union { unsigned int u[4]; short8 v; } ua;
            ua.u[0] = p[0];
            ua.u[1] = p[1];
            ua.u[2] = p[2] & 0xFFFFu;
            ua.u[3] = 0;
            acc = __builtin_amdgcn_mfma_f32_16x16x32_bf16(ua.v, fb[s], acc, 0, 0, 0);
        }
        int YP = 4 * yc + rp;
        int xp = (x0 >> 1) + g;
        if (m < 6 && YP < 254 && (x0 + 2 * g + 1) < 508) {
            float mx = fmaxf(fmaxf(acc[0], acc[1]), fmaxf(acc[2], acc[3])) + bv;
            act1[((size_t)(b * 6 + m) * 254 + YP) * 254 + xp] = f2bf(sigmf(mx));
        }
    }
}

// ============================ conv2 (MFMA) =================================
#define C2_W     144
#define C2_ROWB  288
#define C2_NR    8
#define C2_ZROW  48
#define C2_ROWS  52
#define C2_PH    (C2_ROWS * C2_ROWB)

__global__ __launch_bounds__(256) void k_conv2(const ushort_t* __restrict__ act1,
                                               const float* __restrict__ w,
                                               const float* __restrict__ bias,
                                               float* __restrict__ act2) {
    __shared__ unsigned char sh[2 * C2_PH];
    const int tid = threadIdx.x;
    const int xc = blockIdx.x, yc = blockIdx.y, b = blockIdx.z;
    const int x0c = xc * 128;

    for (int i = tid; i < 2 * 4 * 72; i += 256) {
        int ph = i / (4 * 72);
        int rr = (i / 72) % 4;
        int cc = i % 72;
        *(unsigned int*)(sh + ph * C2_PH + (C2_ZROW + rr) * C2_ROWB + cc * 4) = 0u;
    }
    for (int ph = 0; ph < 2; ++ph) {
        for (int i = tid; i < 6 * C2_NR * 72; i += 256) {
            int plane = i / (C2_NR * 72);
            int rr = (i / 72) % C2_NR;
            int cc = (i % 72) * 2;
            int gr = 4 * yc + rr;
            int gx = x0c + cc + ph;
            const ushort_t* ip = act1 + ((size_t)(b * 6 + plane) * 254 + gr) * 254;
            unsigned int h0 = (gr < 254 && gx < 254) ? ip[gx] : 0;
            unsigned int h1 = (gr < 254 && gx + 1 < 254) ? ip[gx + 1] : 0;
            *(unsigned int*)(sh + ph * C2_PH + (plane * C2_NR + rr) * C2_ROWB + cc * 2) =
                h0 | (h1 << 16);
        }
    }

    const int lane = tid & 63;
    const int g = lane >> 4;
    const int m = lane & 15;

    short8 fb[8];
#pragma unroll
    for (int s = 0; s < 8; ++s) {
        int t = 4 * s + g;
        unsigned int u0 = 0, u1 = 0, u2 = 0;
        if (t < 30) {
            int ic = t / 5, ky = t % 5;
            const float* wp = w + ((m * 6 + ic) * 5 + ky) * 5;
            u0 = (unsigned int)f2bf(wp[0]) | ((unsigned int)f2bf(wp[1]) << 16);
            u1 = (unsigned int)f2bf(wp[2]) | ((unsigned int)f2bf(wp[3]) << 16);
            u2 = (unsigned int)f2bf(wp[4]);
        }
        union { unsigned int u[4]; short8 v; } uu;
        uu.u[0] = u0; uu.u[1] = u1; uu.u[2] = u2; uu.u[3] = 0;
        fb[s] = uu.v;
    }
    unsigned int offv[8];
#pragma unroll
    for (int s = 0; s < 8; ++s) {
        int t = 4 * s + g;
        offv[s] = (t < 30) ? (unsigned int)(((t / 5) * C2_NR + (t % 5)) * C2_ROWB)
                           : (unsigned int)(C2_ZROW * C2_ROWB);
    }
    const float bv = bias[m];
    __syncthreads();

    const int wv = tid >> 6;
    const int par = m & 1;
    const int mh = m >> 1;
    for (int it = wv; it < 32; it += 4) {
        int rp = it >> 4, xt = it & 15;
        int x0 = x0c + xt * 8;
        int xcol = x0 + mh;
        int phi = xcol & 1;
        int i0 = (xcol - x0c) & ~1;
        const unsigned char* base = sh + phi * C2_PH + (2 * rp + par) * C2_ROWB + i0 * 2;
        f32x4 acc = {0.f, 0.f, 0.f, 0.f};
#pragma unroll
        for (int s = 0; s < 8; ++s) {
            const unsigned int* p = (const unsigned int*)(base + offv[s]);
            union { unsigned int u[4]; short8 v; } ua;
            ua.u[0] = p[0];
            ua.u[1] = p[1];
            ua.u[2] = p[2] & 0xFFFFu;
            ua.u[3] = 0;
            acc = __builtin_amdgcn_mfma_f32_16x16x32_bf16(ua.v, fb[s], acc, 0, 0, 0);
        }
        int YP = 2 * yc + rp;
        int xp = (x0 >> 1) + g;
        if (YP < 125 && (x0 + 2 * g + 1) < 250) {
            float mx = fmaxf(fmaxf(acc[0], acc[1]), fmaxf(acc[2], acc[3])) + bv;
            act2[((size_t)(b * 16 + m) * 125 + YP) * 125 + xp] = sigmf(mx);
        }
    }
}

// ---------------- fc0 partials (R5: streaming W, o-tiled) ----------------
// X = act2 (16,250000) f32; W = fc0_w (120,250000). grid (489, 5):
// x = k-block (512 k), y = o-tile (24 o). Block = 4 waves; wave k-span 128.
// Lane l: s = l&7 (k-slice, 4 k), ol = l>>3 (o-lane). Lane handles 3 o rows
// (o = o0 + t*8 + ol) x 16 batches. W load instr = 8 rows x 128 B = 1 KB
// distinct, coalesced streaming. X staged in 32 KB LDS; no shfl in hot loop.
#define FC0_KBLK 512
#define FC0_NB   489

__global__ __launch_bounds__(256) void k_fc0(const float* __restrict__ x,
                                             const float* __restrict__ w,
                                             float* __restrict__ partial) {
    __shared__ float sX[16][FC0_KBLK];
    __shared__ float sY[4][3][8][16];
    const int tid = threadIdx.x;
    const int blk = blockIdx.x;
    const int k0 = blk * FC0_KBLK;
    const int o0 = blockIdx.y * 24;
    const int valid = min(FC0_KBLK, 250000 - k0);

    // stage X[16][512] (zero-padded tail)
    for (int i = tid; i < 16 * (FC0_KBLK / 4); i += 256) {
        int b = i >> 7, j = (i & 127) * 4;
        float4 v = make_float4(0.f, 0.f, 0.f, 0.f);
        if (j < valid) v = *(const float4*)(x + (size_t)b * 250000 + k0 + j);
        *(float4*)(&sX[b][j]) = v;
    }
    __syncthreads();

    const int wv = tid >> 6, l = tid & 63;
    const int s = l & 7, ol = l >> 3;
    const int kwb = wv * 128;

    const float* wrow[3];
#pragma unroll
    for (int t = 0; t < 3; ++t)
        wrow[t] = w + (size_t)(o0 + t * 8 + ol) * 250000 + k0;

    float acc[3][16];
#pragma unroll
    for (int t = 0; t < 3; ++t)
#pragma unroll
        for (int b = 0; b < 16; ++b) acc[t][b] = 0.f;

    const int kwmax = 249996 - k0;  // clamp for W addr (X is 0 there)
#pragma unroll
    for (int c = 0; c < 4; ++c) {
        const int kc = kwb + c * 32 + s * 4;
        const int kw4 = (kc < kwmax) ? kc : kwmax;
        float4 wf0 = *(const float4*)(wrow[0] + kw4);
        float4 wf1 = *(const float4*)(wrow[1] + kw4);
        float4 wf2 = *(const float4*)(wrow[2] + kw4);
#pragma unroll
        for (int b = 0; b < 16; ++b) {
            float4 xv = *(const float4*)(&sX[b][kc]);
            acc[0][b] = fmaf(xv.x, wf0.x, acc[0][b]);
            acc[0][b] = fmaf(xv.y, wf0.y, acc[0][b]);
            acc[0][b] = fmaf(xv.z, wf0.z, acc[0][b]);
            acc[0][b] = fmaf(xv.w, wf0.w, acc[0][b]);
            acc[1][b] = fmaf(xv.x, wf1.x, acc[1][b]);
            acc[1][b] = fmaf(xv.y, wf1.y, acc[1][b]);
            acc[1][b] = fmaf(xv.z, wf1.z, acc[1][b]);
            acc[1][b] = fmaf(xv.w, wf1.w, acc[1][b]);
            acc[2][b] = fmaf(xv.x, wf2.x, acc[2][b]);
            acc[2][b] = fmaf(xv.y, wf2.y, acc[2][b]);
            acc[2][b] = fmaf(xv.z, wf2.z, acc[2][b]);
            acc[2][b] = fmaf(xv.w, wf2.w, acc[2][b]);
        }
    }

    // reduce over s (lanes xor 1,2,4), once per block
#pragma unroll
    for (int t = 0; t < 3; ++t)
#pragma unroll
        for (int b = 0; b < 16; ++b) {
            float a = acc[t][b];
            a += __shfl_xor(a, 1);
            a += __shfl_xor(a, 2);
            a += __shfl_xor(a, 4);
            acc[t][b] = a;
        }
    if (s == 0) {
#pragma unroll
        for (int t = 0; t < 3; ++t)
#pragma unroll
            for (int b = 0; b < 16; ++b) sY[wv][t][ol][b] = acc[t][b];
    }
    __syncthreads();

    float* pp = partial + (size_t)blk * 1920;
    for (int i = tid; i < 384; i += 256) {
        int oo = i >> 4, b = i & 15;
        int t = oo >> 3, olx = oo & 7;
        float v = sY[0][t][olx][b] + sY[1][t][olx][b] +
                  sY[2][t][olx][b] + sY[3][t][olx][b];
        pp[(o0 + oo) * 16 + b] = v;
    }
}

// ---------------- fc0 reduce + bias + sigmoid ----------------
__global__ __launch_bounds__(256) void k_fc0red(const float* __restrict__ partial,
                                                const float* __restrict__ b0,
                                                float* __restrict__ h0) {
    const int tid = threadIdx.x;
    const int wv = tid >> 6, l = tid & 63;
    const int i = blockIdx.x * 4 + wv;
    float s = 0.0f;
    for (int c = l; c < FC0_NB; c += 64) s += partial[(size_t)c * 1920 + i];
    s += __shfl_xor(s, 1);
    s += __shfl_xor(s, 2);
    s += __shfl_xor(s, 4);
    s += __shfl_xor(s, 8);
    s += __shfl_xor(s, 16);
    s += __shfl_xor(s, 32);
    if (l == 0) {
        int o = i >> 4, bb = i & 15;
        h0[bb * 120 + o] = sigmf(s + b0[o]);
    }
}

__global__ __launch_bounds__(256) void k_fctail(const float* __restrict__ h0in,
                                                const float* __restrict__ fc1_w,
                                                const float* __restrict__ fc1_b,
                                                const float* __restrict__ fc2_w,
                                                const float* __restrict__ fc2_b,
                                                const float* __restrict__ gb1,
                                                const float* __restrict__ gb2,
                                                const float* __restrict__ base1,
                                                float* __restrict__ params) {
    __shared__ float sh0[1920];
    __shared__ float sh1[16][84];
    __shared__ float sout[16][10];
    const int tid = threadIdx.x;

    for (int i = tid; i < 1920; i += 256) sh0[i] = h0in[i];
    __syncthreads();

    for (int i = tid; i < 16 * 84; i += 256) {
        int bb = i / 84, o = i % 84;
        float a = fc1_b[o];
        for (int k = 0; k < 120; ++k) a = fmaf(sh0[bb * 120 + k], fc1_w[o * 120 + k], a);
        sh1[bb][o] = sigmf(a);
    }
    __syncthreads();

    for (int i = tid; i < 160; i += 256) {
        int bb = i / 10, o = i % 10;
        float a = fc2_b[o];
        for (int k = 0; k < 84; ++k) a = fmaf(sh1[bb][k], fc2_w[o * 84 + k], a);
        sout[bb][o] = a;
    }
    __syncthreads();

    if (tid < 16) {
        int bb = tid;
        float g1 = sout[bb][0] + gb1[0];
        float g2 = sout[bb][1] + gb2[0];
        float gain = 0.0f;
        for (int j = 0; j < 8; ++j) gain += sout[bb][2 + j] + base1[j];
        params[bb] = g1;
        params[16 + bb] = g2;
        params[32 + bb] = gain;
    }
}

__global__ __launch_bounds__(256) void k_final(const float* __restrict__ img,
                                               const float* __restrict__ params,
                                               float* __restrict__ out) {
    int idx = blockIdx.x * 256 + threadIdx.x;
    int p = idx * 4;
    int b = p >> 18;
    int hw = p & 262143;
    size_t base = ((size_t)b * 3) * 262144 + hw;

    float4 r = *(const float4*)(img + base);
    float4 g = *(const float4*)(img + base + 262144);
    float4 bl = *(const float4*)(img + base + 2 * 262144);
    float g1 = params[b], g2 = params[16 + b], gain = params[32 + b];

    float4 o0, o1, o2;
#pragma unroll
    for (int e = 0; e < 4; ++e) {
        float re = (&r.x)[e], ge = (&g.x)[e], be = (&bl.x)[e];
        float I = (re + ge + be) * (1.0f / 3.0f);
        float gv = (I > 0.5f) ? g2 : g1;
        (&o0.x)[e] = __powf(fminf(fmaxf(re * gain, EPSF), 1.0f), gv);
        (&o1.x)[e] = __powf(fminf(fmaxf(ge * gain, EPSF), 1.0f), gv);
        (&o2.x)[e] = __powf(fminf(fmaxf(be * gain, EPSF), 1.0f), gv);
    }
    *(float4*)(out + base) = o0;
    *(float4*)(out + base + 262144) = o1;
    *(float4*)(out + base + 2 * 262144) = o2;
}

// ---------------------------------------------------------------------------
extern "C" void kernel_launch(void* const* d_in, const int* in_sizes, int n_in,
                              void* d_out, int out_size, void* d_ws, size_t ws_size,
                              hipStream_t stream) {
    const float* img     = (const float*)d_in[0];
    const float* conv1_w = (const float*)d_in[1];
    const float* conv1_b = (const float*)d_in[2];
    const float* conv2_w = (const float*)d_in[3];
    const float* conv2_b = (const float*)d_in[4];
    const float* fc0_w   = (const float*)d_in[5];
    const float* fc0_b   = (const float*)d_in[6];
    const float* fc1_w   = (const float*)d_in[7];
    const float* fc1_b   = (const float*)d_in[8];
    const float* fc2_w   = (const float*)d_in[9];
    const float* fc2_b   = (const float*)d_in[10];
    const float* gb1     = (const float*)d_in[11];
    const float* gb2     = (const float*)d_in[12];
    const float* base1   = (const float*)d_in[13];

    float* outp = (float*)d_out;
    ushort_t* act1 = (ushort_t*)outp;           // 6,193,536 bf16
    float* act2    = outp + 3096768;            // 4,000,000 f32
    float* partial = outp + 7096768;            // 938,880
    float* h0      = outp + 8035648;            // 1,920
    float* params  = (float*)d_ws;              // 48 floats

    k_conv1<<<dim3(4, 64, 16), dim3(256), 0, stream>>>(img, conv1_w, conv1_b, act1);
    k_conv2<<<dim3(2, 63, 16), dim3(256), 0, stream>>>(act1, conv2_w, conv2_b, act2);
    k_fc0<<<dim3(FC0_NB, 5), dim3(256), 0, stream>>>(act2, fc0_w, partial);
    k_fc0red<<<dim3(480), dim3(256), 0, stream>>>(partial, fc0_b, h0);
    k_fctail<<<dim3(1), dim3(256), 0, stream>>>(h0, fc1_w, fc1_b, fc2_w, fc2_b,
                                                gb1, gb2, base1, params);
    k_final<<<dim3(4096), dim3(256), 0, stream>>>(img, params, outp);
}

// Round 6
// 196.467 us; speedup vs baseline: 1.7500x; 1.1559x over previous
//
#include <hip/hip_runtime.h>
#include <hip/hip_bf16.h>
#include <math.h>

// ---------------------------------------------------------------------------
// LeNet-ish forward, MFMA convs (single-copy LDS + alignbit windows).
// Scratch inside d_out (float units):
//  [0)          act1 (bf16, rows padded to 256) 16*6*254*256 u16 = 3,121,152 f
//  [3,121,152)  act2 (f32)   4,000,000
//  [7,121,152)  fc0 partials 489*1920 = 938,880
//  [8,060,032)  h0           1,920
// d_ws: params g1[16], g2[16], gain[16]
// ---------------------------------------------------------------------------

#define EPSF 1e-8f
typedef unsigned short ushort_t;
typedef __attribute__((ext_vector_type(8))) short short8;
typedef __attribute__((ext_vector_type(4))) float f32x4;

__device__ __forceinline__ float sigmf(float x) {
    return 1.0f / (1.0f + __expf(-x));
}
__device__ __forceinline__ unsigned short f2bf(float f) {
    unsigned int u = __float_as_uint(f);
    unsigned int r = (u + 0x7FFFu + ((u >> 16) & 1u)) >> 16;
    return (unsigned short)r;
}
// funnel shift: returns 32 bits of {hi:lo} >> sh (sh in {0,16})
__device__ __forceinline__ unsigned alignb(unsigned hi, unsigned lo, unsigned sh) {
    return (unsigned)((((unsigned long long)hi << 32) | lo) >> sh);
}

// ============================ conv1 (MFMA) =================================
// img (16,3,512,512) f32 -> act1 (16,6,254,[256]) bf16, sigmoid(maxpool+bias)
// Block: (xc 0..3, yc 0..31, b). 8 pooled rows x 64 pooled x per block.
// LDS: single copy, 3 planes x 20 rows x 144 bf16 (288 B rows).
#define C1_ROWB  288

__global__ __launch_bounds__(256) void k_conv1(const float* __restrict__ img,
                                               const float* __restrict__ w,
                                               const float* __restrict__ bias,
                                               ushort_t* __restrict__ act1) {
    __shared__ unsigned char sh[60 * C1_ROWB];  // 17280 B
    const int tid = threadIdx.x;
    const int xc = blockIdx.x, yc = blockIdx.y, b = blockIdx.z;
    const int x0c = xc * 128;

    // stage: 3 planes x 20 rows x 36 float4
    for (int i = tid; i < 2160; i += 256) {
        int plane = i / 720;
        int r20 = (i / 36) % 20;
        int c4 = i % 36;
        int gr = 16 * yc + r20;
        int gx = x0c + c4 * 4;
        float4 v = make_float4(0.f, 0.f, 0.f, 0.f);
        if (gr < 512) {
            const float* ip = img + ((size_t)(b * 3 + plane) * 512 + gr) * 512;
            if (gx + 3 < 512) {
                v = *(const float4*)(ip + gx);
            } else {
                if (gx < 512) v.x = ip[gx];
                if (gx + 1 < 512) v.y = ip[gx + 1];
                if (gx + 2 < 512) v.z = ip[gx + 2];
            }
        }
        unsigned int lo = (unsigned int)f2bf(v.x) | ((unsigned int)f2bf(v.y) << 16);
        unsigned int hi = (unsigned int)f2bf(v.z) | ((unsigned int)f2bf(v.w) << 16);
        *(uint2*)(sh + (plane * 20 + r20) * C1_ROWB + c4 * 8) = make_uint2(lo, hi);
    }

    const int lane = tid & 63;
    const int g = lane >> 4;       // k-group
    const int m = lane & 15;       // D col = oc ; A row = position (par,mh)
    const int par = m & 1;
    const int mh = m >> 1;
    const unsigned sh16 = (unsigned)((mh & 1) << 4);

    // B fragments: taps t=4s+g; fold gray channel (w3/3) into rgb
    const int ocw = (m < 6) ? m : 0;
    short8 fb[4];
#pragma unroll
    for (int s = 0; s < 4; ++s) {
        int t = 4 * s + g;
        unsigned int u0 = 0, u1 = 0, u2 = 0;
        if (t < 15 && m < 6) {
            int ic = t / 5, ky = t % 5;
            const float* wp = w + ((ocw * 4 + ic) * 5 + ky) * 5;
            const float* w3 = w + ((ocw * 4 + 3) * 5 + ky) * 5;
            float v0 = wp[0] + w3[0] * (1.f / 3.f);
            float v1 = wp[1] + w3[1] * (1.f / 3.f);
            float v2 = wp[2] + w3[2] * (1.f / 3.f);
            float v3 = wp[3] + w3[3] * (1.f / 3.f);
            float v4 = wp[4] + w3[4] * (1.f / 3.f);
            u0 = (unsigned int)f2bf(v0) | ((unsigned int)f2bf(v1) << 16);
            u1 = (unsigned int)f2bf(v2) | ((unsigned int)f2bf(v3) << 16);
            u2 = (unsigned int)f2bf(v4);
        }
        union { unsigned int u[4]; short8 v; } uu;
        uu.u[0] = u0; uu.u[1] = u1; uu.u[2] = u2; uu.u[3] = 0;
        fb[s] = uu.v;
    }
    // A row offsets per tap (pad taps read row 0: B=0 there, product is 0)
    unsigned int offv[4];
#pragma unroll
    for (int s = 0; s < 4; ++s) {
        int t = 4 * s + g;
        offv[s] = (t < 15) ? (unsigned int)(((t / 5) * 20 + (t % 5)) * C1_ROWB) : 0u;
    }
    const float bv = (m < 6) ? bias[m] : 0.f;
    __syncthreads();

    const int wv = tid >> 6;
    for (int it = wv; it < 128; it += 4) {
        int rp = it >> 4, xt = it & 15;
        int x0 = x0c + xt * 8;
        int i0 = (xt * 8 + mh) & ~1;
        const unsigned char* base = sh + (2 * rp + par) * C1_ROWB + i0 * 2;
        f32x4 acc = {0.f, 0.f, 0.f, 0.f};
#pragma unroll
        for (int s = 0; s < 4; ++s) {
            const unsigned int* p = (const unsigned int*)(base + offv[s]);
            unsigned d0 = p[0], d1 = p[1], d2 = p[2];
            union { unsigned int u[4]; short8 v; } ua;
            ua.u[0] = alignb(d1, d0, sh16);
            ua.u[1] = alignb(d2, d1, sh16);
            ua.u[2] = (d2 >> sh16) & 0xFFFFu;
            ua.u[3] = 0;
            acc = __builtin_amdgcn_mfma_f32_16x16x32_bf16(ua.v, fb[s], acc, 0, 0, 0);
        }
        int YP = 8 * yc + rp;
        int xp = (x0 >> 1) + g;
        if (m < 6 && YP < 254 && (x0 + 2 * g + 1) < 508) {
            float mx = fmaxf(fmaxf(acc[0], acc[1]), fmaxf(acc[2], acc[3])) + bv;
            act1[((size_t)(b * 6 + m) * 254 + YP) * 256 + xp] = f2bf(sigmf(mx));
        }
    }
}

// ============================ conv2 (MFMA) =================================
// act1 (16,6,254,[256]) bf16 -> act2 (16,16,125,125) f32
// Block: (xc 0..1, yc 0..31, b). 4 pooled rows x 64 pooled x per block.
// LDS: single copy, 6 planes x 12 rows x 144 bf16.
#define C2_ROWB  288

__global__ __launch_bounds__(256) void k_conv2(const ushort_t* __restrict__ act1,
                                               const float* __restrict__ w,
                                               const float* __restrict__ bias,
                                               float* __restrict__ act2) {
    __shared__ unsigned char sh[72 * C2_ROWB];  // 20736 B
    const int tid = threadIdx.x;
    const int xc = blockIdx.x, yc = blockIdx.y, b = blockIdx.z;
    const int x0c = xc * 128;

    // stage: 6 planes x 12 rows x 36 x (4 bf16)
    for (int i = tid; i < 2592; i += 256) {
        int plane = i / 432;
        int r12 = (i / 36) % 12;
        int c4 = i % 36;
        int gr = 8 * yc + r12;
        int gx = x0c + c4 * 4;
        uint2 v = make_uint2(0u, 0u);
        if (gr < 254 && gx + 3 < 256) {
            const ushort_t* ip = act1 + ((size_t)(b * 6 + plane) * 254 + gr) * 256;
            v = *(const uint2*)(ip + gx);
        }
        *(uint2*)(sh + (plane * 12 + r12) * C2_ROWB + c4 * 8) = v;
    }

    const int lane = tid & 63;
    const int g = lane >> 4;
    const int m = lane & 15;     // oc
    const int par = m & 1;
    const int mh = m >> 1;
    const unsigned sh16 = (unsigned)((mh & 1) << 4);

    short8 fb[8];
#pragma unroll
    for (int s = 0; s < 8; ++s) {
        int t = 4 * s + g;
        unsigned int u0 = 0, u1 = 0, u2 = 0;
        if (t < 30) {
            int ic = t / 5, ky = t % 5;
            const float* wp = w + ((m * 6 + ic) * 5 + ky) * 5;
            u0 = (unsigned int)f2bf(wp[0]) | ((unsigned int)f2bf(wp[1]) << 16);
            u1 = (unsigned int)f2bf(wp[2]) | ((unsigned int)f2bf(wp[3]) << 16);
            u2 = (unsigned int)f2bf(wp[4]);
        }
        union { unsigned int u[4]; short8 v; } uu;
        uu.u[0] = u0; uu.u[1] = u1; uu.u[2] = u2; uu.u[3] = 0;
        fb[s] = uu.v;
    }
    unsigned int offv[8];
#pragma unroll
    for (int s = 0; s < 8; ++s) {
        int t = 4 * s + g;
        offv[s] = (t < 30) ? (unsigned int)(((t / 5) * 12 + (t % 5)) * C2_ROWB) : 0u;
    }
    const float bv = bias[m];
    __syncthreads();

    const int wv = tid >> 6;
    for (int it = wv; it < 64; it += 4) {
        int rp = it >> 4, xt = it & 15;
        int x0 = x0c + xt * 8;
        int i0 = (xt * 8 + mh) & ~1;
        const unsigned char* base = sh + (2 * rp + par) * C2_ROWB + i0 * 2;
        f32x4 acc = {0.f, 0.f, 0.f, 0.f};
#pragma unroll
        for (int s = 0; s < 8; ++s) {
            const unsigned int* p = (const unsigned int*)(base + offv[s]);
            unsigned d0 = p[0], d1 = p[1], d2 = p[2];
            union { unsigned int u[4]; short8 v; } ua;
            ua.u[0] = alignb(d1, d0, sh16);
            ua.u[1] = alignb(d2, d1, sh16);
            ua.u[2] = (d2 >> sh16) & 0xFFFFu;
            ua.u[3] = 0;
            acc = __builtin_amdgcn_mfma_f32_16x16x32_bf16(ua.v, fb[s], acc, 0, 0, 0);
        }
        int YP = 4 * yc + rp;
        int xp = (x0 >> 1) + g;
        if (YP < 125 && (x0 + 2 * g + 1) < 250) {
            float mx = fmaxf(fmaxf(acc[0], acc[1]), fmaxf(acc[2], acc[3])) + bv;
            act2[((size_t)(b * 16 + m) * 125 + YP) * 125 + xp] = sigmf(mx);
        }
    }
}

// ---------------- fc0 partials (streaming W, o-tiled) ----------------
#define FC0_KBLK 512
#define FC0_NB   489

__global__ __launch_bounds__(256) void k_fc0(const float* __restrict__ x,
                                             const float* __restrict__ w,
                                             float* __restrict__ partial) {
    __shared__ float sX[16][FC0_KBLK];
    __shared__ float sY[4][3][8][16];
    const int tid = threadIdx.x;
    const int blk = blockIdx.x;
    const int k0 = blk * FC0_KBLK;
    const int o0 = blockIdx.y * 24;
    const int valid = min(FC0_KBLK, 250000 - k0);

    for (int i = tid; i < 16 * (FC0_KBLK / 4); i += 256) {
        int b = i >> 7, j = (i & 127) * 4;
        float4 v = make_float4(0.f, 0.f, 0.f, 0.f);
        if (j < valid) v = *(const float4*)(x + (size_t)b * 250000 + k0 + j);
        *(float4*)(&sX[b][j]) = v;
    }
    __syncthreads();

    const int wv = tid >> 6, l = tid & 63;
    const int s = l & 7, ol = l >> 3;
    const int kwb = wv * 128;

    const float* wrow[3];
#pragma unroll
    for (int t = 0; t < 3; ++t)
        wrow[t] = w + (size_t)(o0 + t * 8 + ol) * 250000 + k0;

    float acc[3][16];
#pragma unroll
    for (int t = 0; t < 3; ++t)
#pragma unroll
        for (int b = 0; b < 16; ++b) acc[t][b] = 0.f;

    const int kwmax = 249996 - k0;
#pragma unroll
    for (int c = 0; c < 4; ++c) {
        const int kc = kwb + c * 32 + s * 4;
        const int kw4 = (kc < kwmax) ? kc : kwmax;
        float4 wf0 = *(const float4*)(wrow[0] + kw4);
        float4 wf1 = *(const float4*)(wrow[1] + kw4);
        float4 wf2 = *(const float4*)(wrow[2] + kw4);
#pragma unroll
        for (int b = 0; b < 16; ++b) {
            float4 xv = *(const float4*)(&sX[b][kc]);
            acc[0][b] = fmaf(xv.x, wf0.x, acc[0][b]);
            acc[0][b] = fmaf(xv.y, wf0.y, acc[0][b]);
            acc[0][b] = fmaf(xv.z, wf0.z, acc[0][b]);
            acc[0][b] = fmaf(xv.w, wf0.w, acc[0][b]);
            acc[1][b] = fmaf(xv.x, wf1.x, acc[1][b]);
            acc[1][b] = fmaf(xv.y, wf1.y, acc[1][b]);
            acc[1][b] = fmaf(xv.z, wf1.z, acc[1][b]);
            acc[1][b] = fmaf(xv.w, wf1.w, acc[1][b]);
            acc[2][b] = fmaf(xv.x, wf2.x, acc[2][b]);
            acc[2][b] = fmaf(xv.y, wf2.y, acc[2][b]);
            acc[2][b] = fmaf(xv.z, wf2.z, acc[2][b]);
            acc[2][b] = fmaf(xv.w, wf2.w, acc[2][b]);
        }
    }

#pragma unroll
    for (int t = 0; t < 3; ++t)
#pragma unroll
        for (int b = 0; b < 16; ++b) {
            float a = acc[t][b];
            a += __shfl_xor(a, 1);
            a += __shfl_xor(a, 2);
            a += __shfl_xor(a, 4);
            acc[t][b] = a;
        }
    if (s == 0) {
#pragma unroll
        for (int t = 0; t < 3; ++t)
#pragma unroll
            for (int b = 0; b < 16; ++b) sY[wv][t][ol][b] = acc[t][b];
    }
    __syncthreads();

    float* pp = partial + (size_t)blk * 1920;
    for (int i = tid; i < 384; i += 256) {
        int oo = i >> 4, b = i & 15;
        int t = oo >> 3, olx = oo & 7;
        float v = sY[0][t][olx][b] + sY[1][t][olx][b] +
                  sY[2][t][olx][b] + sY[3][t][olx][b];
        pp[(o0 + oo) * 16 + b] = v;
    }
}

// ---------------- fc0 reduce + bias + sigmoid ----------------
__global__ __launch_bounds__(256) void k_fc0red(const float* __restrict__ partial,
                                                const float* __restrict__ b0,
                                                float* __restrict__ h0) {
    const int tid = threadIdx.x;
    const int wv = tid >> 6, l = tid & 63;
    const int i = blockIdx.x * 4 + wv;
    float s = 0.0f;
    for (int c = l; c < FC0_NB; c += 64) s += partial[(size_t)c * 1920 + i];
    s += __shfl_xor(s, 1);
    s += __shfl_xor(s, 2);
    s += __shfl_xor(s, 4);
    s += __shfl_xor(s, 8);
    s += __shfl_xor(s, 16);
    s += __shfl_xor(s, 32);
    if (l == 0) {
        int o = i >> 4, bb = i & 15;
        h0[bb * 120 + o] = sigmf(s + b0[o]);
    }
}

__global__ __launch_bounds__(256) void k_fctail(const float* __restrict__ h0in,
                                                const float* __restrict__ fc1_w,
                                                const float* __restrict__ fc1_b,
                                                const float* __restrict__ fc2_w,
                                                const float* __restrict__ fc2_b,
                                                const float* __restrict__ gb1,
                                                const float* __restrict__ gb2,
                                                const float* __restrict__ base1,
                                                float* __restrict__ params) {
    __shared__ float sh0[1920];
    __shared__ float sh1[16][84];
    __shared__ float sout[16][10];
    const int tid = threadIdx.x;

    for (int i = tid; i < 1920; i += 256) sh0[i] = h0in[i];
    __syncthreads();

    for (int i = tid; i < 16 * 84; i += 256) {
        int bb = i / 84, o = i % 84;
        float a = fc1_b[o];
        for (int k = 0; k < 120; ++k) a = fmaf(sh0[bb * 120 + k], fc1_w[o * 120 + k], a);
        sh1[bb][o] = sigmf(a);
    }
    __syncthreads();

    for (int i = tid; i < 160; i += 256) {
        int bb = i / 10, o = i % 10;
        float a = fc2_b[o];
        for (int k = 0; k < 84; ++k) a = fmaf(sh1[bb][k], fc2_w[o * 84 + k], a);
        sout[bb][o] = a;
    }
    __syncthreads();

    if (tid < 16) {
        int bb = tid;
        float g1 = sout[bb][0] + gb1[0];
        float g2 = sout[bb][1] + gb2[0];
        float gain = 0.0f;
        for (int j = 0; j < 8; ++j) gain += sout[bb][2 + j] + base1[j];
        params[bb] = g1;
        params[16 + bb] = g2;
        params[32 + bb] = gain;
    }
}

__global__ __launch_bounds__(256) void k_final(const float* __restrict__ img,
                                               const float* __restrict__ params,
                                               float* __restrict__ out) {
    int idx = blockIdx.x * 256 + threadIdx.x;
    int p = idx * 4;
    int b = p >> 18;
    int hw = p & 262143;
    size_t base = ((size_t)b * 3) * 262144 + hw;

    float4 r = *(const float4*)(img + base);
    float4 g = *(const float4*)(img + base + 262144);
    float4 bl = *(const float4*)(img + base + 2 * 262144);
    float g1 = params[b], g2 = params[16 + b], gain = params[32 + b];

    float4 o0, o1, o2;
#pragma unroll
    for (int e = 0; e < 4; ++e) {
        float re = (&r.x)[e], ge = (&g.x)[e], be = (&bl.x)[e];
        float I = (re + ge + be) * (1.0f / 3.0f);
        float gv = (I > 0.5f) ? g2 : g1;
        (&o0.x)[e] = __powf(fminf(fmaxf(re * gain, EPSF), 1.0f), gv);
        (&o1.x)[e] = __powf(fminf(fmaxf(ge * gain, EPSF), 1.0f), gv);
        (&o2.x)[e] = __powf(fminf(fmaxf(be * gain, EPSF), 1.0f), gv);
    }
    *(float4*)(out + base) = o0;
    *(float4*)(out + base + 262144) = o1;
    *(float4*)(out + base + 2 * 262144) = o2;
}

// ---------------------------------------------------------------------------
extern "C" void kernel_launch(void* const* d_in, const int* in_sizes, int n_in,
                              void* d_out, int out_size, void* d_ws, size_t ws_size,
                              hipStream_t stream) {
    const float* img     = (const float*)d_in[0];
    const float* conv1_w = (const float*)d_in[1];
    const float* conv1_b = (const float*)d_in[2];
    const float* conv2_w = (const float*)d_in[3];
    const float* conv2_b = (const float*)d_in[4];
    const float* fc0_w   = (const float*)d_in[5];
    const float* fc0_b   = (const float*)d_in[6];
    const float* fc1_w   = (const float*)d_in[7];
    const float* fc1_b   = (const float*)d_in[8];
    const float* fc2_w   = (const float*)d_in[9];
    const float* fc2_b   = (const float*)d_in[10];
    const float* gb1     = (const float*)d_in[11];
    const float* gb2     = (const float*)d_in[12];
    const float* base1   = (const float*)d_in[13];

    float* outp = (float*)d_out;
    ushort_t* act1 = (ushort_t*)outp;           // 16*6*254*256 bf16 (padded rows)
    float* act2    = outp + 3121152;            // 4,000,000 f32
    float* partial = outp + 7121152;            // 938,880
    float* h0      = outp + 8060032;            // 1,920
    float* params  = (float*)d_ws;              // 48 floats

    k_conv1<<<dim3(4, 32, 16), dim3(256), 0, stream>>>(img, conv1_w, conv1_b, act1);
    k_conv2<<<dim3(2, 32, 16), dim3(256), 0, stream>>>(act1, conv2_w, conv2_b, act2);
    k_fc0<<<dim3(FC0_NB, 5), dim3(256), 0, stream>>>(act2, fc0_w, partial);
    k_fc0red<<<dim3(480), dim3(256), 0, stream>>>(partial, fc0_b, h0);
    k_fctail<<<dim3(1), dim3(256), 0, stream>>>(h0, fc1_w, fc1_b, fc2_w, fc2_b,
                                                gb1, gb2, base1, params);
    k_final<<<dim3(4096), dim3(256), 0, stream>>>(img, params, outp);
}

// Round 7
// 193.503 us; speedup vs baseline: 1.7768x; 1.0153x over previous
//
#include <hip/hip_runtime.h>
#include <hip/hip_bf16.h>
#include <math.h>

// ---------------------------------------------------------------------------
// LeNet-ish forward, MFMA convs (single-copy LDS + alignbit windows).
// Scratch inside d_out (float units):
//  [0)          act1 (bf16, rows padded to 256) 16*6*254*256 u16 = 3,121,152 f
//  [3,121,152)  act2 (f32)   4,000,000
//  [7,121,152)  fc0 partials 489*1920 = 938,880
//  [8,060,032)  h0           1,920
// d_ws: params g1[16], g2[16], gain[16]
// ---------------------------------------------------------------------------

#define EPSF 1e-8f
typedef unsigned short ushort_t;
typedef __attribute__((ext_vector_type(8))) short short8;
typedef __attribute__((ext_vector_type(4))) float f32x4;

__device__ __forceinline__ float sigmf(float x) {
    return 1.0f / (1.0f + __expf(-x));
}
__device__ __forceinline__ unsigned short f2bf(float f) {
    unsigned int u = __float_as_uint(f);
    unsigned int r = (u + 0x7FFFu + ((u >> 16) & 1u)) >> 16;
    return (unsigned short)r;
}
// funnel shift: returns 32 bits of {hi:lo} >> sh (sh in {0,16})
__device__ __forceinline__ unsigned alignb(unsigned hi, unsigned lo, unsigned sh) {
    return (unsigned)((((unsigned long long)hi << 32) | lo) >> sh);
}

// ============================ conv1 (MFMA) =================================
#define C1_ROWB  288

__global__ __launch_bounds__(256) void k_conv1(const float* __restrict__ img,
                                               const float* __restrict__ w,
                                               const float* __restrict__ bias,
                                               ushort_t* __restrict__ act1) {
    __shared__ unsigned char sh[60 * C1_ROWB];  // 17280 B
    const int tid = threadIdx.x;
    const int xc = blockIdx.x, yc = blockIdx.y, b = blockIdx.z;
    const int x0c = xc * 128;

    for (int i = tid; i < 2160; i += 256) {
        int plane = i / 720;
        int r20 = (i / 36) % 20;
        int c4 = i % 36;
        int gr = 16 * yc + r20;
        int gx = x0c + c4 * 4;
        float4 v = make_float4(0.f, 0.f, 0.f, 0.f);
        if (gr < 512) {
            const float* ip = img + ((size_t)(b * 3 + plane) * 512 + gr) * 512;
            if (gx + 3 < 512) {
                v = *(const float4*)(ip + gx);
            } else {
                if (gx < 512) v.x = ip[gx];
                if (gx + 1 < 512) v.y = ip[gx + 1];
                if (gx + 2 < 512) v.z = ip[gx + 2];
            }
        }
        unsigned int lo = (unsigned int)f2bf(v.x) | ((unsigned int)f2bf(v.y) << 16);
        unsigned int hi = (unsigned int)f2bf(v.z) | ((unsigned int)f2bf(v.w) << 16);
        *(uint2*)(sh + (plane * 20 + r20) * C1_ROWB + c4 * 8) = make_uint2(lo, hi);
    }

    const int lane = tid & 63;
    const int g = lane >> 4;
    const int m = lane & 15;
    const int par = m & 1;
    const int mh = m >> 1;
    const unsigned sh16 = (unsigned)((mh & 1) << 4);

    const int ocw = (m < 6) ? m : 0;
    short8 fb[4];
#pragma unroll
    for (int s = 0; s < 4; ++s) {
        int t = 4 * s + g;
        unsigned int u0 = 0, u1 = 0, u2 = 0;
        if (t < 15 && m < 6) {
            int ic = t / 5, ky = t % 5;
            const float* wp = w + ((ocw * 4 + ic) * 5 + ky) * 5;
            const float* w3 = w + ((ocw * 4 + 3) * 5 + ky) * 5;
            float v0 = wp[0] + w3[0] * (1.f / 3.f);
            float v1 = wp[1] + w3[1] * (1.f / 3.f);
            float v2 = wp[2] + w3[2] * (1.f / 3.f);
            float v3 = wp[3] + w3[3] * (1.f / 3.f);
            float v4 = wp[4] + w3[4] * (1.f / 3.f);
            u0 = (unsigned int)f2bf(v0) | ((unsigned int)f2bf(v1) << 16);
            u1 = (unsigned int)f2bf(v2) | ((unsigned int)f2bf(v3) << 16);
            u2 = (unsigned int)f2bf(v4);
        }
        union { unsigned int u[4]; short8 v; } uu;
        uu.u[0] = u0; uu.u[1] = u1; uu.u[2] = u2; uu.u[3] = 0;
        fb[s] = uu.v;
    }
    unsigned int offv[4];
#pragma unroll
    for (int s = 0; s < 4; ++s) {
        int t = 4 * s + g;
        offv[s] = (t < 15) ? (unsigned int)(((t / 5) * 20 + (t % 5)) * C1_ROWB) : 0u;
    }
    const float bv = (m < 6) ? bias[m] : 0.f;
    __syncthreads();

    const int wv = tid >> 6;
    for (int it = wv; it < 128; it += 4) {
        int rp = it >> 4, xt = it & 15;
        int x0 = x0c + xt * 8;
        int i0 = (xt * 8 + mh) & ~1;
        const unsigned char* base = sh + (2 * rp + par) * C1_ROWB + i0 * 2;
        f32x4 acc = {0.f, 0.f, 0.f, 0.f};
#pragma unroll
        for (int s = 0; s < 4; ++s) {
            const unsigned int* p = (const unsigned int*)(base + offv[s]);
            unsigned d0 = p[0], d1 = p[1], d2 = p[2];
            union { unsigned int u[4]; short8 v; } ua;
            ua.u[0] = alignb(d1, d0, sh16);
            ua.u[1] = alignb(d2, d1, sh16);
            ua.u[2] = (d2 >> sh16) & 0xFFFFu;
            ua.u[3] = 0;
            acc = __builtin_amdgcn_mfma_f32_16x16x32_bf16(ua.v, fb[s], acc, 0, 0, 0);
        }
        int YP = 8 * yc + rp;
        int xp = (x0 >> 1) + g;
        if (m < 6 && YP < 254 && (x0 + 2 * g + 1) < 508) {
            float mx = fmaxf(fmaxf(acc[0], acc[1]), fmaxf(acc[2], acc[3])) + bv;
            act1[((size_t)(b * 6 + m) * 254 + YP) * 256 + xp] = f2bf(sigmf(mx));
        }
    }
}

// ============================ conv2 (MFMA) =================================
#define C2_ROWB  288

__global__ __launch_bounds__(256) void k_conv2(const ushort_t* __restrict__ act1,
                                               const float* __restrict__ w,
                                               const float* __restrict__ bias,
                                               float* __restrict__ act2) {
    __shared__ unsigned char sh[72 * C2_ROWB];  // 20736 B
    const int tid = threadIdx.x;
    const int xc = blockIdx.x, yc = blockIdx.y, b = blockIdx.z;
    const int x0c = xc * 128;

    for (int i = tid; i < 2592; i += 256) {
        int plane = i / 432;
        int r12 = (i / 36) % 12;
        int c4 = i % 36;
        int gr = 8 * yc + r12;
        int gx = x0c + c4 * 4;
        uint2 v = make_uint2(0u, 0u);
        if (gr < 254 && gx + 3 < 256) {
            const ushort_t* ip = act1 + ((size_t)(b * 6 + plane) * 254 + gr) * 256;
            v = *(const uint2*)(ip + gx);
        }
        *(uint2*)(sh + (plane * 12 + r12) * C2_ROWB + c4 * 8) = v;
    }

    const int lane = tid & 63;
    const int g = lane >> 4;
    const int m = lane & 15;
    const int par = m & 1;
    const int mh = m >> 1;
    const unsigned sh16 = (unsigned)((mh & 1) << 4);

    short8 fb[8];
#pragma unroll
    for (int s = 0; s < 8; ++s) {
        int t = 4 * s + g;
        unsigned int u0 = 0, u1 = 0, u2 = 0;
        if (t < 30) {
            int ic = t / 5, ky = t % 5;
            const float* wp = w + ((m * 6 + ic) * 5 + ky) * 5;
            u0 = (unsigned int)f2bf(wp[0]) | ((unsigned int)f2bf(wp[1]) << 16);
            u1 = (unsigned int)f2bf(wp[2]) | ((unsigned int)f2bf(wp[3]) << 16);
            u2 = (unsigned int)f2bf(wp[4]);
        }
        union { unsigned int u[4]; short8 v; } uu;
        uu.u[0] = u0; uu.u[1] = u1; uu.u[2] = u2; uu.u[3] = 0;
        fb[s] = uu.v;
    }
    unsigned int offv[8];
#pragma unroll
    for (int s = 0; s < 8; ++s) {
        int t = 4 * s + g;
        offv[s] = (t < 30) ? (unsigned int)(((t / 5) * 12 + (t % 5)) * C2_ROWB) : 0u;
    }
    const float bv = bias[m];
    __syncthreads();

    const int wv = tid >> 6;
    for (int it = wv; it < 64; it += 4) {
        int rp = it >> 4, xt = it & 15;
        int x0 = x0c + xt * 8;
        int i0 = (xt * 8 + mh) & ~1;
        const unsigned char* base = sh + (2 * rp + par) * C2_ROWB + i0 * 2;
        f32x4 acc = {0.f, 0.f, 0.f, 0.f};
#pragma unroll
        for (int s = 0; s < 8; ++s) {
            const unsigned int* p = (const unsigned int*)(base + offv[s]);
            unsigned d0 = p[0], d1 = p[1], d2 = p[2];
            union { unsigned int u[4]; short8 v; } ua;
            ua.u[0] = alignb(d1, d0, sh16);
            ua.u[1] = alignb(d2, d1, sh16);
            ua.u[2] = (d2 >> sh16) & 0xFFFFu;
            ua.u[3] = 0;
            acc = __builtin_amdgcn_mfma_f32_16x16x32_bf16(ua.v, fb[s], acc, 0, 0, 0);
        }
        int YP = 4 * yc + rp;
        int xp = (x0 >> 1) + g;
        if (YP < 125 && (x0 + 2 * g + 1) < 250) {
            float mx = fmaxf(fmaxf(acc[0], acc[1]), fmaxf(acc[2], acc[3])) + bv;
            act2[((size_t)(b * 16 + m) * 125 + YP) * 125 + xp] = sigmf(mx);
        }
    }
}

// ---------------- fc0 partials (R7: deep-preload streaming) ----------------
// X = act2 (16,250000) f32; W = fc0_w (120,250000). grid (489, 8):
// x = k-block (512 k), y = o-tile (16 o, rows >=120 clamped+guarded).
// Block = 4 waves; wave k-span 128. Lane: s = l&7 (k-slice), ol = l>>3.
// Lane handles 2 o rows x 16 batches; ALL 8 W float4 preloaded before FMA
// (8 KB/wave in flight). W load instr = 8 rows x 128 B coalesced.
#define FC0_KBLK 512
#define FC0_NB   489

__global__ __launch_bounds__(256) void k_fc0(const float* __restrict__ x,
                                             const float* __restrict__ w,
                                             float* __restrict__ partial) {
    __shared__ float sX[16][FC0_KBLK];
    __shared__ float sY[4][2][8][16];
    const int tid = threadIdx.x;
    const int blk = blockIdx.x;
    const int k0 = blk * FC0_KBLK;
    const int o0 = blockIdx.y * 16;
    const int valid = min(FC0_KBLK, 250000 - k0);

    for (int i = tid; i < 16 * (FC0_KBLK / 4); i += 256) {
        int b = i >> 7, j = (i & 127) * 4;
        float4 v = make_float4(0.f, 0.f, 0.f, 0.f);
        if (j < valid) v = *(const float4*)(x + (size_t)b * 250000 + k0 + j);
        *(float4*)(&sX[b][j]) = v;
    }
    __syncthreads();

    const int wv = tid >> 6, l = tid & 63;
    const int s = l & 7, ol = l >> 3;
    const int kwb = wv * 128;

    const int or0 = min(o0 + ol, 119);
    const int or1 = min(o0 + 8 + ol, 119);
    const float* wr0 = w + (size_t)or0 * 250000 + k0;
    const float* wr1 = w + (size_t)or1 * 250000 + k0;

    const int kwmax = 249996 - k0;
    int kc[4], kw4[4];
#pragma unroll
    for (int c = 0; c < 4; ++c) {
        kc[c] = kwb + c * 32 + s * 4;
        kw4[c] = (kc[c] < kwmax) ? kc[c] : kwmax;
    }

    // preload: 8 independent coalesced 16B loads in flight
    float4 wf0[4], wf1[4];
#pragma unroll
    for (int c = 0; c < 4; ++c) {
        wf0[c] = *(const float4*)(wr0 + kw4[c]);
        wf1[c] = *(const float4*)(wr1 + kw4[c]);
    }

    float acc0[16], acc1[16];
#pragma unroll
    for (int b = 0; b < 16; ++b) { acc0[b] = 0.f; acc1[b] = 0.f; }

#pragma unroll
    for (int c = 0; c < 4; ++c) {
#pragma unroll
        for (int b = 0; b < 16; ++b) {
            float4 xv = *(const float4*)(&sX[b][kc[c]]);
            acc0[b] = fmaf(xv.x, wf0[c].x, acc0[b]);
            acc0[b] = fmaf(xv.y, wf0[c].y, acc0[b]);
            acc0[b] = fmaf(xv.z, wf0[c].z, acc0[b]);
            acc0[b] = fmaf(xv.w, wf0[c].w, acc0[b]);
            acc1[b] = fmaf(xv.x, wf1[c].x, acc1[b]);
            acc1[b] = fmaf(xv.y, wf1[c].y, acc1[b]);
            acc1[b] = fmaf(xv.z, wf1[c].z, acc1[b]);
            acc1[b] = fmaf(xv.w, wf1[c].w, acc1[b]);
        }
    }

#pragma unroll
    for (int b = 0; b < 16; ++b) {
        float a0 = acc0[b], a1 = acc1[b];
        a0 += __shfl_xor(a0, 1); a1 += __shfl_xor(a1, 1);
        a0 += __shfl_xor(a0, 2); a1 += __shfl_xor(a1, 2);
        a0 += __shfl_xor(a0, 4); a1 += __shfl_xor(a1, 4);
        acc0[b] = a0; acc1[b] = a1;
    }
    if (s == 0) {
#pragma unroll
        for (int b = 0; b < 16; ++b) {
            sY[wv][0][ol][b] = acc0[b];
            sY[wv][1][ol][b] = acc1[b];
        }
    }
    __syncthreads();

    float* pp = partial + (size_t)blk * 1920;
    for (int i = tid; i < 256; i += 256) {
        int oo = i >> 4, b = i & 15;        // oo 0..15
        int t = oo >> 3, olx = oo & 7;
        if (o0 + oo < 120) {
            float v = sY[0][t][olx][b] + sY[1][t][olx][b] +
                      sY[2][t][olx][b] + sY[3][t][olx][b];
            pp[(o0 + oo) * 16 + b] = v;
        }
    }
}

// ---------------- fc0 reduce + bias + sigmoid ----------------
__global__ __launch_bounds__(256) void k_fc0red(const float* __restrict__ partial,
                                                const float* __restrict__ b0,
                                                float* __restrict__ h0) {
    const int tid = threadIdx.x;
    const int wv = tid >> 6, l = tid & 63;
    const int i = blockIdx.x * 4 + wv;
    float s = 0.0f;
    for (int c = l; c < FC0_NB; c += 64) s += partial[(size_t)c * 1920 + i];
    s += __shfl_xor(s, 1);
    s += __shfl_xor(s, 2);
    s += __shfl_xor(s, 4);
    s += __shfl_xor(s, 8);
    s += __shfl_xor(s, 16);
    s += __shfl_xor(s, 32);
    if (l == 0) {
        int o = i >> 4, bb = i & 15;
        h0[bb * 120 + o] = sigmf(s + b0[o]);
    }
}

__global__ __launch_bounds__(256) void k_fctail(const float* __restrict__ h0in,
                                                const float* __restrict__ fc1_w,
                                                const float* __restrict__ fc1_b,
                                                const float* __restrict__ fc2_w,
                                                const float* __restrict__ fc2_b,
                                                const float* __restrict__ gb1,
                                                const float* __restrict__ gb2,
                                                const float* __restrict__ base1,
                                                float* __restrict__ params) {
    __shared__ float sh0[1920];
    __shared__ float sh1[16][84];
    __shared__ float sout[16][10];
    const int tid = threadIdx.x;

    for (int i = tid; i < 1920; i += 256) sh0[i] = h0in[i];
    __syncthreads();

    for (int i = tid; i < 16 * 84; i += 256) {
        int bb = i / 84, o = i % 84;
        float a = fc1_b[o];
        for (int k = 0; k < 120; ++k) a = fmaf(sh0[bb * 120 + k], fc1_w[o * 120 + k], a);
        sh1[bb][o] = sigmf(a);
    }
    __syncthreads();

    for (int i = tid; i < 160; i += 256) {
        int bb = i / 10, o = i % 10;
        float a = fc2_b[o];
        for (int k = 0; k < 84; ++k) a = fmaf(sh1[bb][k], fc2_w[o * 84 + k], a);
        sout[bb][o] = a;
    }
    __syncthreads();

    if (tid < 16) {
        int bb = tid;
        float g1 = sout[bb][0] + gb1[0];
        float g2 = sout[bb][1] + gb2[0];
        float gain = 0.0f;
        for (int j = 0; j < 8; ++j) gain += sout[bb][2 + j] + base1[j];
        params[bb] = g1;
        params[16 + bb] = g2;
        params[32 + bb] = gain;
    }
}

__global__ __launch_bounds__(256) void k_final(const float* __restrict__ img,
                                               const float* __restrict__ params,
                                               float* __restrict__ out) {
    int idx = blockIdx.x * 256 + threadIdx.x;
    int p = idx * 4;
    int b = p >> 18;
    int hw = p & 262143;
    size_t base = ((size_t)b * 3) * 262144 + hw;

    float4 r = *(const float4*)(img + base);
    float4 g = *(const float4*)(img + base + 262144);
    float4 bl = *(const float4*)(img + base + 2 * 262144);
    float g1 = params[b], g2 = params[16 + b], gain = params[32 + b];

    float4 o0, o1, o2;
#pragma unroll
    for (int e = 0; e < 4; ++e) {
        float re = (&r.x)[e], ge = (&g.x)[e], be = (&bl.x)[e];
        float I = (re + ge + be) * (1.0f / 3.0f);
        float gv = (I > 0.5f) ? g2 : g1;
        (&o0.x)[e] = __powf(fminf(fmaxf(re * gain, EPSF), 1.0f), gv);
        (&o1.x)[e] = __powf(fminf(fmaxf(ge * gain, EPSF), 1.0f), gv);
        (&o2.x)[e] = __powf(fminf(fmaxf(be * gain, EPSF), 1.0f), gv);
    }
    *(float4*)(out + base) = o0;
    *(float4*)(out + base + 262144) = o1;
    *(float4*)(out + base + 2 * 262144) = o2;
}

// ---------------------------------------------------------------------------
extern "C" void kernel_launch(void* const* d_in, const int* in_sizes, int n_in,
                              void* d_out, int out_size, void* d_ws, size_t ws_size,
                              hipStream_t stream) {
    const float* img     = (const float*)d_in[0];
    const float* conv1_w = (const float*)d_in[1];
    const float* conv1_b = (const float*)d_in[2];
    const float* conv2_w = (const float*)d_in[3];
    const float* conv2_b = (const float*)d_in[4];
    const float* fc0_w   = (const float*)d_in[5];
    const float* fc0_b   = (const float*)d_in[6];
    const float* fc1_w   = (const float*)d_in[7];
    const float* fc1_b   = (const float*)d_in[8];
    const float* fc2_w   = (const float*)d_in[9];
    const float* fc2_b   = (const float*)d_in[10];
    const float* gb1     = (const float*)d_in[11];
    const float* gb2     = (const float*)d_in[12];
    const float* base1   = (const float*)d_in[13];

    float* outp = (float*)d_out;
    ushort_t* act1 = (ushort_t*)outp;           // 16*6*254*256 bf16 (padded rows)
    float* act2    = outp + 3121152;            // 4,000,000 f32
    float* partial = outp + 7121152;            // 938,880
    float* h0      = outp + 8060032;            // 1,920
    float* params  = (float*)d_ws;              // 48 floats

    k_conv1<<<dim3(4, 32, 16), dim3(256), 0, stream>>>(img, conv1_w, conv1_b, act1);
    k_conv2<<<dim3(2, 32, 16), dim3(256), 0, stream>>>(act1, conv2_w, conv2_b, act2);
    k_fc0<<<dim3(FC0_NB, 8), dim3(256), 0, stream>>>(act2, fc0_w, partial);
    k_fc0red<<<dim3(480), dim3(256), 0, stream>>>(partial, fc0_b, h0);
    k_fctail<<<dim3(1), dim3(256), 0, stream>>>(h0, fc1_w, fc1_b, fc2_w, fc2_b,
                                                gb1, gb2, base1, params);
    k_final<<<dim3(4096), dim3(256), 0, stream>>>(img, params, outp);
}

// Round 8
// 173.980 us; speedup vs baseline: 1.9762x; 1.1122x over previous
//
#include <hip/hip_runtime.h>
#include <hip/hip_bf16.h>
#include <math.h>

// ---------------------------------------------------------------------------
// LeNet-ish forward, MFMA convs + MFMA fc0. Scratch inside d_out (float):
//  [0)          act1 (bf16, rows padded to 256) 16*6*254*256 u16 = 3,121,152 f
//  [3,121,152)  act2 (f32)   4,000,000
//  [7,121,152)  fc0 partials 489*1920 = 938,880
//  [8,060,032)  h0           1,920
// d_ws: params g1[16], g2[16], gain[16]
// ---------------------------------------------------------------------------

#define EPSF 1e-8f
typedef unsigned short ushort_t;
typedef __attribute__((ext_vector_type(8))) short short8;
typedef __attribute__((ext_vector_type(4))) float f32x4;

__device__ __forceinline__ float sigmf(float x) {
    return 1.0f / (1.0f + __expf(-x));
}
__device__ __forceinline__ unsigned short f2bf(float f) {
    unsigned int u = __float_as_uint(f);
    unsigned int r = (u + 0x7FFFu + ((u >> 16) & 1u)) >> 16;
    return (unsigned short)r;
}
// pack two floats to bf16x2 (round-half-up; inputs are finite smalls)
__device__ __forceinline__ unsigned pk2bf(float a, float b) {
    unsigned ua = __float_as_uint(a), ub = __float_as_uint(b);
    return ((ua + 0x8000u) >> 16) | ((ub + 0x8000u) & 0xFFFF0000u);
}
// funnel shift: returns 32 bits of {hi:lo} >> sh (sh in {0,16})
__device__ __forceinline__ unsigned alignb(unsigned hi, unsigned lo, unsigned sh) {
    return (unsigned)((((unsigned long long)hi << 32) | lo) >> sh);
}

// ============================ conv1 (MFMA) =================================
#define C1_ROWB  288

__global__ __launch_bounds__(256) void k_conv1(const float* __restrict__ img,
                                               const float* __restrict__ w,
                                               const float* __restrict__ bias,
                                               ushort_t* __restrict__ act1) {
    __shared__ unsigned char sh[60 * C1_ROWB];  // 17280 B
    const int tid = threadIdx.x;
    const int xc = blockIdx.x, yc = blockIdx.y, b = blockIdx.z;
    const int x0c = xc * 128;

    for (int i = tid; i < 2160; i += 256) {
        int plane = i / 720;
        int r20 = (i / 36) % 20;
        int c4 = i % 36;
        int gr = 16 * yc + r20;
        int gx = x0c + c4 * 4;
        float4 v = make_float4(0.f, 0.f, 0.f, 0.f);
        if (gr < 512) {
            const float* ip = img + ((size_t)(b * 3 + plane) * 512 + gr) * 512;
            if (gx + 3 < 512) {
                v = *(const float4*)(ip + gx);
            } else {
                if (gx < 512) v.x = ip[gx];
                if (gx + 1 < 512) v.y = ip[gx + 1];
                if (gx + 2 < 512) v.z = ip[gx + 2];
            }
        }
        unsigned int lo = (unsigned int)f2bf(v.x) | ((unsigned int)f2bf(v.y) << 16);
        unsigned int hi = (unsigned int)f2bf(v.z) | ((unsigned int)f2bf(v.w) << 16);
        *(uint2*)(sh + (plane * 20 + r20) * C1_ROWB + c4 * 8) = make_uint2(lo, hi);
    }

    const int lane = tid & 63;
    const int g = lane >> 4;
    const int m = lane & 15;
    const int par = m & 1;
    const int mh = m >> 1;
    const unsigned sh16 = (unsigned)((mh & 1) << 4);

    const int ocw = (m < 6) ? m : 0;
    short8 fb[4];
#pragma unroll
    for (int s = 0; s < 4; ++s) {
        int t = 4 * s + g;
        unsigned int u0 = 0, u1 = 0, u2 = 0;
        if (t < 15 && m < 6) {
            int ic = t / 5, ky = t % 5;
            const float* wp = w + ((ocw * 4 + ic) * 5 + ky) * 5;
            const float* w3 = w + ((ocw * 4 + 3) * 5 + ky) * 5;
            float v0 = wp[0] + w3[0] * (1.f / 3.f);
            float v1 = wp[1] + w3[1] * (1.f / 3.f);
            float v2 = wp[2] + w3[2] * (1.f / 3.f);
            float v3 = wp[3] + w3[3] * (1.f / 3.f);
            float v4 = wp[4] + w3[4] * (1.f / 3.f);
            u0 = (unsigned int)f2bf(v0) | ((unsigned int)f2bf(v1) << 16);
            u1 = (unsigned int)f2bf(v2) | ((unsigned int)f2bf(v3) << 16);
            u2 = (unsigned int)f2bf(v4);
        }
        union { unsigned int u[4]; short8 v; } uu;
        uu.u[0] = u0; uu.u[1] = u1; uu.u[2] = u2; uu.u[3] = 0;
        fb[s] = uu.v;
    }
    unsigned int offv[4];
#pragma unroll
    for (int s = 0; s < 4; ++s) {
        int t = 4 * s + g;
        offv[s] = (t < 15) ? (unsigned int)(((t / 5) * 20 + (t % 5)) * C1_ROWB) : 0u;
    }
    const float bv = (m < 6) ? bias[m] : 0.f;
    __syncthreads();

    const int wv = tid >> 6;
    for (int it = wv; it < 128; it += 4) {
        int rp = it >> 4, xt = it & 15;
        int x0 = x0c + xt * 8;
        int i0 = (xt * 8 + mh) & ~1;
        const unsigned char* base = sh + (2 * rp + par) * C1_ROWB + i0 * 2;
        f32x4 acc = {0.f, 0.f, 0.f, 0.f};
#pragma unroll
        for (int s = 0; s < 4; ++s) {
            const unsigned int* p = (const unsigned int*)(base + offv[s]);
            unsigned d0 = p[0], d1 = p[1], d2 = p[2];
            union { unsigned int u[4]; short8 v; } ua;
            ua.u[0] = alignb(d1, d0, sh16);
            ua.u[1] = alignb(d2, d1, sh16);
            ua.u[2] = (d2 >> sh16) & 0xFFFFu;
            ua.u[3] = 0;
            acc = __builtin_amdgcn_mfma_f32_16x16x32_bf16(ua.v, fb[s], acc, 0, 0, 0);
        }
        int YP = 8 * yc + rp;
        int xp = (x0 >> 1) + g;
        if (m < 6 && YP < 254 && (x0 + 2 * g + 1) < 508) {
            float mx = fmaxf(fmaxf(acc[0], acc[1]), fmaxf(acc[2], acc[3])) + bv;
            act1[((size_t)(b * 6 + m) * 254 + YP) * 256 + xp] = f2bf(sigmf(mx));
        }
    }
}

// ============================ conv2 (MFMA) =================================
#define C2_ROWB  288

__global__ __launch_bounds__(256) void k_conv2(const ushort_t* __restrict__ act1,
                                               const float* __restrict__ w,
                                               const float* __restrict__ bias,
                                               float* __restrict__ act2) {
    __shared__ unsigned char sh[72 * C2_ROWB];  // 20736 B
    const int tid = threadIdx.x;
    const int xc = blockIdx.x, yc = blockIdx.y, b = blockIdx.z;
    const int x0c = xc * 128;

    for (int i = tid; i < 2592; i += 256) {
        int plane = i / 432;
        int r12 = (i / 36) % 12;
        int c4 = i % 36;
        int gr = 8 * yc + r12;
        int gx = x0c + c4 * 4;
        uint2 v = make_uint2(0u, 0u);
        if (gr < 254 && gx + 3 < 256) {
            const ushort_t* ip = act1 + ((size_t)(b * 6 + plane) * 254 + gr) * 256;
            v = *(const uint2*)(ip + gx);
        }
        *(uint2*)(sh + (plane * 12 + r12) * C2_ROWB + c4 * 8) = v;
    }

    const int lane = tid & 63;
    const int g = lane >> 4;
    const int m = lane & 15;
    const int par = m & 1;
    const int mh = m >> 1;
    const unsigned sh16 = (unsigned)((mh & 1) << 4);

    short8 fb[8];
#pragma unroll
    for (int s = 0; s < 8; ++s) {
        int t = 4 * s + g;
        unsigned int u0 = 0, u1 = 0, u2 = 0;
        if (t < 30) {
            int ic = t / 5, ky = t % 5;
            const float* wp = w + ((m * 6 + ic) * 5 + ky) * 5;
            u0 = (unsigned int)f2bf(wp[0]) | ((unsigned int)f2bf(wp[1]) << 16);
            u1 = (unsigned int)f2bf(wp[2]) | ((unsigned int)f2bf(wp[3]) << 16);
            u2 = (unsigned int)f2bf(wp[4]);
        }
        union { unsigned int u[4]; short8 v; } uu;
        uu.u[0] = u0; uu.u[1] = u1; uu.u[2] = u2; uu.u[3] = 0;
        fb[s] = uu.v;
    }
    unsigned int offv[8];
#pragma unroll
    for (int s = 0; s < 8; ++s) {
        int t = 4 * s + g;
        offv[s] = (t < 30) ? (unsigned int)(((t / 5) * 12 + (t % 5)) * C2_ROWB) : 0u;
    }
    const float bv = bias[m];
    __syncthreads();

    const int wv = tid >> 6;
    for (int it = wv; it < 64; it += 4) {
        int rp = it >> 4, xt = it & 15;
        int x0 = x0c + xt * 8;
        int i0 = (xt * 8 + mh) & ~1;
        const unsigned char* base = sh + (2 * rp + par) * C2_ROWB + i0 * 2;
        f32x4 acc = {0.f, 0.f, 0.f, 0.f};
#pragma unroll
        for (int s = 0; s < 8; ++s) {
            const unsigned int* p = (const unsigned int*)(base + offv[s]);
            unsigned d0 = p[0], d1 = p[1], d2 = p[2];
            union { unsigned int u[4]; short8 v; } ua;
            ua.u[0] = alignb(d1, d0, sh16);
            ua.u[1] = alignb(d2, d1, sh16);
            ua.u[2] = (d2 >> sh16) & 0xFFFFu;
            ua.u[3] = 0;
            acc = __builtin_amdgcn_mfma_f32_16x16x32_bf16(ua.v, fb[s], acc, 0, 0, 0);
        }
        int YP = 4 * yc + rp;
        int xp = (x0 >> 1) + g;
        if (YP < 125 && (x0 + 2 * g + 1) < 250) {
            float mx = fmaxf(fmaxf(acc[0], acc[1]), fmaxf(acc[2], acc[3])) + bv;
            act2[((size_t)(b * 16 + m) * 125 + YP) * 125 + xp] = sigmf(mx);
        }
    }
}

// ---------------- fc0 partials (R8: MFMA GEMM, streaming W) ----------------
// y[16b][120o] = X(16,250000) . W^T, K split over 489 blocks of 512.
// Block = 4 waves; wave k-span 128. X staged once as bf16 in LDS (XOR
// swizzled). Each wave: 4 A-frags in regs (reused for all o), then 8 o-tiles:
// per tile 8 coalesced W float4 loads -> pack bf16 -> 4 MFMAs.
// D layout (16x16x32): col=lane&15=o, row=(lane>>4)*4+i=batch.
#define FC0_KBLK 512
#define FC0_NB   489

__global__ __launch_bounds__(256) void k_fc0(const float* __restrict__ x,
                                             const float* __restrict__ w,
                                             float* __restrict__ partial) {
    __shared__ ushort_t sX[16 * FC0_KBLK];   // 16 KB bf16, row stride 1024 B
    __shared__ float sY[4][128][17];         // 34.8 KB, padded
    const int tid = threadIdx.x;
    const int blk = blockIdx.x;
    const int k0 = blk * FC0_KBLK;
    const int valid = min(FC0_KBLK, 250000 - k0);

    // stage X as bf16, XOR-swizzled rows (byte ^= (row&7)<<4)
    for (int i = tid; i < 16 * (FC0_KBLK / 4); i += 256) {
        int b = i >> 7;
        int j = (i & 127) * 4;
        float4 v = make_float4(0.f, 0.f, 0.f, 0.f);
        if (j < valid) v = *(const float4*)(x + (size_t)b * 250000 + k0 + j);
        unsigned lo = (unsigned)f2bf(v.x) | ((unsigned)f2bf(v.y) << 16);
        unsigned hi = (unsigned)f2bf(v.z) | ((unsigned)f2bf(v.w) << 16);
        unsigned byte = (unsigned)(b * 1024 + j * 2) ^ (unsigned)((b & 7) << 4);
        *(uint2*)((unsigned char*)sX + byte) = make_uint2(lo, hi);
    }
    __syncthreads();

    const int wv = tid >> 6, lane = tid & 63;
    const int g = lane >> 4, m = lane & 15;
    const int kw = wv * 128;

    // A-frags: frag s holds X[row=m][kw + s*32 + g*8 .. +7]
    short8 fa[4];
#pragma unroll
    for (int s = 0; s < 4; ++s) {
        unsigned byte = (unsigned)(m * 1024 + (kw + s * 32 + g * 8) * 2)
                        ^ (unsigned)((m & 7) << 4);
        fa[s] = *(const short8*)((const unsigned char*)sX + byte);
    }

    const int kwmax = (250000 - k0) - 4;  // last valid float4 start

#pragma unroll 2
    for (int nt = 0; nt < 8; ++nt) {
        const int o0 = nt * 16;
        const int orow = min(o0 + m, 119);
        const float* wr = w + (size_t)orow * 250000 + k0;
        f32x4 acc = {0.f, 0.f, 0.f, 0.f};
#pragma unroll
        for (int s = 0; s < 4; ++s) {
            int kc = kw + s * 32 + g * 8;
            int ka = (kc < kwmax) ? kc : kwmax;
            int kb = (kc + 4 < kwmax) ? kc + 4 : kwmax;
            float4 w0 = *(const float4*)(wr + ka);
            float4 w1 = *(const float4*)(wr + kb);
            union { unsigned u[4]; short8 v; } ub;
            ub.u[0] = pk2bf(w0.x, w0.y);
            ub.u[1] = pk2bf(w0.z, w0.w);
            ub.u[2] = pk2bf(w1.x, w1.y);
            ub.u[3] = pk2bf(w1.z, w1.w);
            acc = __builtin_amdgcn_mfma_f32_16x16x32_bf16(fa[s], ub.v, acc, 0, 0, 0);
        }
#pragma unroll
        for (int i = 0; i < 4; ++i) sY[wv][o0 + m][g * 4 + i] = acc[i];
    }
    __syncthreads();

    // cross-wave reduce -> partial[blk][o*16+b]
    float* pp = partial + (size_t)blk * 1920;
    for (int i = tid; i < 1920; i += 256) {
        int o = i >> 4, b = i & 15;
        pp[i] = sY[0][o][b] + sY[1][o][b] + sY[2][o][b] + sY[3][o][b];
    }
}

// ---------------- fc0 reduce + bias + sigmoid ----------------
__global__ __launch_bounds__(256) void k_fc0red(const float* __restrict__ partial,
                                                const float* __restrict__ b0,
                                                float* __restrict__ h0) {
    const int tid = threadIdx.x;
    const int wv = tid >> 6, l = tid & 63;
    const int i = blockIdx.x * 4 + wv;
    float s = 0.0f;
    for (int c = l; c < FC0_NB; c += 64) s += partial[(size_t)c * 1920 + i];
    s += __shfl_xor(s, 1);
    s += __shfl_xor(s, 2);
    s += __shfl_xor(s, 4);
    s += __shfl_xor(s, 8);
    s += __shfl_xor(s, 16);
    s += __shfl_xor(s, 32);
    if (l == 0) {
        int o = i >> 4, bb = i & 15;
        h0[bb * 120 + o] = sigmf(s + b0[o]);
    }
}

__global__ __launch_bounds__(256) void k_fctail(const float* __restrict__ h0in,
                                                const float* __restrict__ fc1_w,
                                                const float* __restrict__ fc1_b,
                                                const float* __restrict__ fc2_w,
                                                const float* __restrict__ fc2_b,
                                                const float* __restrict__ gb1,
                                                const float* __restrict__ gb2,
                                                const float* __restrict__ base1,
                                                float* __restrict__ params) {
    __shared__ float sh0[1920];
    __shared__ float sh1[16][84];
    __shared__ float sout[16][10];
    const int tid = threadIdx.x;

    for (int i = tid; i < 1920; i += 256) sh0[i] = h0in[i];
    __syncthreads();

    for (int i = tid; i < 16 * 84; i += 256) {
        int bb = i / 84, o = i % 84;
        float a = fc1_b[o];
        for (int k = 0; k < 120; ++k) a = fmaf(sh0[bb * 120 + k], fc1_w[o * 120 + k], a);
        sh1[bb][o] = sigmf(a);
    }
    __syncthreads();

    for (int i = tid; i < 160; i += 256) {
        int bb = i / 10, o = i % 10;
        float a = fc2_b[o];
        for (int k = 0; k < 84; ++k) a = fmaf(sh1[bb][k], fc2_w[o * 84 + k], a);
        sout[bb][o] = a;
    }
    __syncthreads();

    if (tid < 16) {
        int bb = tid;
        float g1 = sout[bb][0] + gb1[0];
        float g2 = sout[bb][1] + gb2[0];
        float gain = 0.0f;
        for (int j = 0; j < 8; ++j) gain += sout[bb][2 + j] + base1[j];
        params[bb] = g1;
        params[16 + bb] = g2;
        params[32 + bb] = gain;
    }
}

__global__ __launch_bounds__(256) void k_final(const float* __restrict__ img,
                                               const float* __restrict__ params,
                                               float* __restrict__ out) {
    int idx = blockIdx.x * 256 + threadIdx.x;
    int p = idx * 4;
    int b = p >> 18;
    int hw = p & 262143;
    size_t base = ((size_t)b * 3) * 262144 + hw;

    float4 r = *(const float4*)(img + base);
    float4 g = *(const float4*)(img + base + 262144);
    float4 bl = *(const float4*)(img + base + 2 * 262144);
    float g1 = params[b], g2 = params[16 + b], gain = params[32 + b];

    float4 o0, o1, o2;
#pragma unroll
    for (int e = 0; e < 4; ++e) {
        float re = (&r.x)[e], ge = (&g.x)[e], be = (&bl.x)[e];
        float I = (re + ge + be) * (1.0f / 3.0f);
        float gv = (I > 0.5f) ? g2 : g1;
        (&o0.x)[e] = __powf(fminf(fmaxf(re * gain, EPSF), 1.0f), gv);
        (&o1.x)[e] = __powf(fminf(fmaxf(ge * gain, EPSF), 1.0f), gv);
        (&o2.x)[e] = __powf(fminf(fmaxf(be * gain, EPSF), 1.0f), gv);
    }
    *(float4*)(out + base) = o0;
    *(float4*)(out + base + 262144) = o1;
    *(float4*)(out + base + 2 * 262144) = o2;
}

// ---------------------------------------------------------------------------
extern "C" void kernel_launch(void* const* d_in, const int* in_sizes, int n_in,
                              void* d_out, int out_size, void* d_ws, size_t ws_size,
                              hipStream_t stream) {
    const float* img     = (const float*)d_in[0];
    const float* conv1_w = (const float*)d_in[1];
    const float* conv1_b = (const float*)d_in[2];
    const float* conv2_w = (const float*)d_in[3];
    const float* conv2_b = (const float*)d_in[4];
    const float* fc0_w   = (const float*)d_in[5];
    const float* fc0_b   = (const float*)d_in[6];
    const float* fc1_w   = (const float*)d_in[7];
    const float* fc1_b   = (const float*)d_in[8];
    const float* fc2_w   = (const float*)d_in[9];
    const float* fc2_b   = (const float*)d_in[10];
    const float* gb1     = (const float*)d_in[11];
    const float* gb2     = (const float*)d_in[12];
    const float* base1   = (const float*)d_in[13];

    float* outp = (float*)d_out;
    ushort_t* act1 = (ushort_t*)outp;           // 16*6*254*256 bf16 (padded rows)
    float* act2    = outp + 3121152;            // 4,000,000 f32
    float* partial = outp + 7121152;            // 938,880
    float* h0      = outp + 8060032;            // 1,920
    float* params  = (float*)d_ws;              // 48 floats

    k_conv1<<<dim3(4, 32, 16), dim3(256), 0, stream>>>(img, conv1_w, conv1_b, act1);
    k_conv2<<<dim3(2, 32, 16), dim3(256), 0, stream>>>(act1, conv2_w, conv2_b, act2);
    k_fc0<<<dim3(FC0_NB), dim3(256), 0, stream>>>(act2, fc0_w, partial);
    k_fc0red<<<dim3(480), dim3(256), 0, stream>>>(partial, fc0_b, h0);
    k_fctail<<<dim3(1), dim3(256), 0, stream>>>(h0, fc1_w, fc1_b, fc2_w, fc2_b,
                                                gb1, gb2, base1, params);
    k_final<<<dim3(4096), dim3(256), 0, stream>>>(img, params, outp);
}

// Round 9
// 160.434 us; speedup vs baseline: 2.1431x; 1.0844x over previous
//
#include <hip/hip_runtime.h>
#include <hip/hip_bf16.h>
#include <math.h>

// ---------------------------------------------------------------------------
// LeNet-ish forward, MFMA convs (dual-phase LDS, +16B phase pad, full unroll)
// + MFMA fc0. Scratch inside d_out (float units):
//  [0)          act1 (bf16, rows padded to 256) 16*6*254*256 u16 = 3,121,152 f
//  [3,121,152)  act2 (f32)   4,000,000
//  [7,121,152)  fc0 partials 489*1920 = 938,880
//  [8,060,032)  h0           1,920
// d_ws: params g1[16], g2[16], gain[16]
// ---------------------------------------------------------------------------

#define EPSF 1e-8f
typedef unsigned short ushort_t;
typedef __attribute__((ext_vector_type(8))) short short8;
typedef __attribute__((ext_vector_type(4))) float f32x4;

__device__ __forceinline__ float sigmf(float x) {
    return 1.0f / (1.0f + __expf(-x));
}
__device__ __forceinline__ unsigned short f2bf(float f) {
    unsigned int u = __float_as_uint(f);
    unsigned int r = (u + 0x7FFFu + ((u >> 16) & 1u)) >> 16;
    return (unsigned short)r;
}
// pack two floats to bf16x2 (round-half-up)
__device__ __forceinline__ unsigned pk2bf(float a, float b) {
    unsigned ua = __float_as_uint(a), ub = __float_as_uint(b);
    return ((ua + 0x8000u) >> 16) | ((ub + 0x8000u) & 0xFFFF0000u);
}

// ============================ conv1 (MFMA) =================================
// img (16,3,512,512) f32 -> act1 (16,6,254,[256]) bf16, sigmoid(maxpool+bias)
// Block (xc 0..3, yc 0..31, b): 8 pooled rows x 64 pooled x.
// LDS: 2 phase copies (phase p element e = data[x0c+e+p]); 3x20 rows x 144.
#define C1_ROWB 288
#define C1_P1   17296          // 60*288 + 16 pad (4-bank shift)

__global__ __launch_bounds__(256) void k_conv1(const float* __restrict__ img,
                                               const float* __restrict__ w,
                                               const float* __restrict__ bias,
                                               ushort_t* __restrict__ act1) {
    __shared__ unsigned char sh[C1_P1 + 60 * C1_ROWB];   // 34576 B
    const int tid = threadIdx.x;
    const int xc = blockIdx.x, yc = blockIdx.y, b = blockIdx.z;
    const int x0c = xc * 128;

    // stage both phases: 3 planes x 20 rows x 36 quads
    for (int i = tid; i < 2160; i += 256) {
        int plane = i / 720;
        int r20 = (i / 36) % 20;
        int c4 = i % 36;
        int gr = 16 * yc + r20;
        int gx = x0c + c4 * 4;
        float v0 = 0.f, v1 = 0.f, v2 = 0.f, v3 = 0.f, v4 = 0.f;
        if (gr < 512 && gx < 512) {
            const float* ip = img + ((size_t)(b * 3 + plane) * 512 + gr) * 512;
            float4 t = *(const float4*)(ip + gx);
            v0 = t.x; v1 = t.y; v2 = t.z; v3 = t.w;
            if (gx + 4 < 512) v4 = ip[gx + 4];
        }
        unsigned bofs = (unsigned)((plane * 20 + r20) * C1_ROWB + c4 * 8);
        *(uint2*)(sh + bofs) = make_uint2(pk2bf(v0, v1), pk2bf(v2, v3));
        *(uint2*)(sh + C1_P1 + bofs) = make_uint2(pk2bf(v1, v2), pk2bf(v3, v4));
    }

    const int lane = tid & 63;
    const int g = lane >> 4;
    const int m = lane & 15;
    const int par = m & 1;
    const int mh = m >> 1;
    const int p = mh & 1;

    // B fragments: taps t=4s+g; fold gray channel (w3/3) into rgb
    const int ocw = (m < 6) ? m : 0;
    short8 fb[4];
#pragma unroll
    for (int s = 0; s < 4; ++s) {
        int t = 4 * s + g;
        unsigned u0 = 0, u1 = 0, u2 = 0;
        if (t < 15 && m < 6) {
            int ic = t / 5, ky = t % 5;
            const float* wp = w + ((ocw * 4 + ic) * 5 + ky) * 5;
            const float* w3 = w + ((ocw * 4 + 3) * 5 + ky) * 5;
            float a0 = wp[0] + w3[0] * (1.f / 3.f);
            float a1 = wp[1] + w3[1] * (1.f / 3.f);
            float a2 = wp[2] + w3[2] * (1.f / 3.f);
            float a3 = wp[3] + w3[3] * (1.f / 3.f);
            float a4 = wp[4] + w3[4] * (1.f / 3.f);
            u0 = pk2bf(a0, a1);
            u1 = pk2bf(a2, a3);
            u2 = pk2bf(a4, 0.f);
        }
        union { unsigned u[4]; short8 v; } uu;
        uu.u[0] = u0; uu.u[1] = u1; uu.u[2] = u2; uu.u[3] = 0;
        fb[s] = uu.v;
    }
    unsigned offv[4];
#pragma unroll
    for (int s = 0; s < 4; ++s) {
        int t = 4 * s + g;
        offv[s] = (t < 15) ? (unsigned)(((t / 5) * 20 + (t % 5)) * C1_ROWB) : 0u;
    }
    const float bv = (m < 6) ? bias[m] : 0.f;
    __syncthreads();

    const int wv = tid >> 6;
    // per-lane read base: phase + par row + lane x-offset + wave xt offset
    const unsigned laneoff = (p ? C1_P1 : 0u) + (unsigned)(par * C1_ROWB)
                             + (unsigned)((mh & ~1) * 2) + (unsigned)(wv * 16);
    // per-lane store base (offsets are compile-time per unrolled it)
    ushort_t* sb = act1 + ((size_t)(b * 6 + ocw) * 254 + 8 * yc) * 256
                   + (x0c >> 1) + wv * 4 + g;
    const bool mok = (m < 6);
    const int YPb = 8 * yc;
    const int xlim = 508 - 2 * g - 1;   // store iff x0 < xlim

#pragma unroll
    for (int rp = 0; rp < 8; ++rp) {
#pragma unroll
        for (int xtq = 0; xtq < 4; ++xtq) {
            const unsigned char* base = sh + laneoff + rp * (2 * C1_ROWB) + xtq * 128;
            f32x4 acc = {0.f, 0.f, 0.f, 0.f};
#pragma unroll
            for (int s = 0; s < 4; ++s) {
                const unsigned* q = (const unsigned*)(base + offv[s]);
                union { unsigned u[4]; short8 v; } ua;
                ua.u[0] = q[0]; ua.u[1] = q[1]; ua.u[2] = q[2]; ua.u[3] = q[3];
                acc = __builtin_amdgcn_mfma_f32_16x16x32_bf16(ua.v, fb[s], acc, 0, 0, 0);
            }
            int xt = xtq * 4 + wv;
            int x0 = x0c + xt * 8;
            if (mok && (YPb + rp) < 254 && x0 < xlim) {
                float mx = fmaxf(fmaxf(acc[0], acc[1]), fmaxf(acc[2], acc[3])) + bv;
                sb[rp * 256 + xtq * 16] = f2bf(sigmf(mx));
            }
        }
    }
}

// ============================ conv2 (MFMA) =================================
// act1 (16,6,254,[256]) bf16 -> act2 (16,16,125,125) f32
// Block (xc 0..1, yc 0..31, b): 4 pooled rows x 64 pooled x.
#define C2_ROWB 288
#define C2_P1   20752          // 72*288 + 16 pad

__global__ __launch_bounds__(256) void k_conv2(const ushort_t* __restrict__ act1,
                                               const float* __restrict__ w,
                                               const float* __restrict__ bias,
                                               float* __restrict__ act2) {
    __shared__ unsigned char sh[C2_P1 + 72 * C2_ROWB];   // 41488 B
    const int tid = threadIdx.x;
    const int xc = blockIdx.x, yc = blockIdx.y, b = blockIdx.z;
    const int x0c = xc * 128;

    // stage: 6 planes x 12 rows x 36 quads (bf16 source)
    for (int i = tid; i < 2592; i += 256) {
        int plane = i / 432;
        int r12 = (i / 36) % 12;
        int c4 = i % 36;
        int gr = 8 * yc + r12;
        int gx = x0c + c4 * 4;
        unsigned d0 = 0, d1 = 0, h4 = 0;
        if (gr < 254 && gx + 3 < 256) {
            const ushort_t* ip = act1 + ((size_t)(b * 6 + plane) * 254 + gr) * 256;
            uint2 t = *(const uint2*)(ip + gx);
            d0 = t.x; d1 = t.y;
            if (gx + 4 < 256) h4 = ip[gx + 4];
        }
        unsigned bofs = (unsigned)((plane * 12 + r12) * C2_ROWB + c4 * 8);
        *(uint2*)(sh + bofs) = make_uint2(d0, d1);
        // phase1: elements shifted by +1: (h1,h2),(h3,h4)
        unsigned e0 = (d0 >> 16) | (d1 << 16);
        unsigned e1 = (d1 >> 16) | (h4 << 16);
        *(uint2*)(sh + C2_P1 + bofs) = make_uint2(e0, e1);
    }

    const int lane = tid & 63;
    const int g = lane >> 4;
    const int m = lane & 15;     // oc
    const int par = m & 1;
    const int mh = m >> 1;
    const int p = mh & 1;

    short8 fb[8];
#pragma unroll
    for (int s = 0; s < 8; ++s) {
        int t = 4 * s + g;
        unsigned u0 = 0, u1 = 0, u2 = 0;
        if (t < 30) {
            int ic = t / 5, ky = t % 5;
            const float* wp = w + ((m * 6 + ic) * 5 + ky) * 5;
            u0 = pk2bf(wp[0], wp[1]);
            u1 = pk2bf(wp[2], wp[3]);
            u2 = pk2bf(wp[4], 0.f);
        }
        union { unsigned u[4]; short8 v; } uu;
        uu.u[0] = u0; uu.u[1] = u1; uu.u[2] = u2; uu.u[3] = 0;
        fb[s] = uu.v;
    }
    unsigned offv[8];
#pragma unroll
    for (int s = 0; s < 8; ++s) {
        int t = 4 * s + g;
        offv[s] = (t < 30) ? (unsigned)(((t / 5) * 12 + (t % 5)) * C2_ROWB) : 0u;
    }
    const float bv = bias[m];
    __syncthreads();

    const int wv = tid >> 6;
    const unsigned laneoff = (p ? C2_P1 : 0u) + (unsigned)(par * C2_ROWB)
                             + (unsigned)((mh & ~1) * 2) + (unsigned)(wv * 16);
    float* sb = act2 + ((size_t)(b * 16 + m) * 125 + 4 * yc) * 125
                + (x0c >> 1) + wv * 4 + g;
    const int YPb = 4 * yc;
    const int xlim = 250 - 2 * g - 1;

#pragma unroll
    for (int rp = 0; rp < 4; ++rp) {
#pragma unroll
        for (int xtq = 0; xtq < 4; ++xtq) {
            const unsigned char* base = sh + laneoff + rp * (2 * C2_ROWB) + xtq * 128;
            f32x4 acc = {0.f, 0.f, 0.f, 0.f};
#pragma unroll
            for (int s = 0; s < 8; ++s) {
                const unsigned* q = (const unsigned*)(base + offv[s]);
                union { unsigned u[4]; short8 v; } ua;
                ua.u[0] = q[0]; ua.u[1] = q[1]; ua.u[2] = q[2]; ua.u[3] = q[3];
                acc = __builtin_amdgcn_mfma_f32_16x16x32_bf16(ua.v, fb[s], acc, 0, 0, 0);
            }
            int xt = xtq * 4 + wv;
            int x0 = x0c + xt * 8;
            if ((YPb + rp) < 125 && x0 < xlim) {
                float mx = fmaxf(fmaxf(acc[0], acc[1]), fmaxf(acc[2], acc[3])) + bv;
                sb[rp * 125 + xtq * 16] = sigmf(mx);
            }
        }
    }
}

// ---------------- fc0 partials (MFMA GEMM, streaming W) ----------------
#define FC0_KBLK 512
#define FC0_NB   489

__global__ __launch_bounds__(256) void k_fc0(const float* __restrict__ x,
                                             const float* __restrict__ w,
                                             float* __restrict__ partial) {
    __shared__ ushort_t sX[16 * FC0_KBLK];   // 16 KB bf16, row stride 1024 B
    __shared__ float sY[4][128][17];
    const int tid = threadIdx.x;
    const int blk = blockIdx.x;
    const int k0 = blk * FC0_KBLK;
    const int valid = min(FC0_KBLK, 250000 - k0);

    for (int i = tid; i < 16 * (FC0_KBLK / 4); i += 256) {
        int b = i >> 7;
        int j = (i & 127) * 4;
        float4 v = make_float4(0.f, 0.f, 0.f, 0.f);
        if (j < valid) v = *(const float4*)(x + (size_t)b * 250000 + k0 + j);
        unsigned lo = (unsigned)f2bf(v.x) | ((unsigned)f2bf(v.y) << 16);
        unsigned hi = (unsigned)f2bf(v.z) | ((unsigned)f2bf(v.w) << 16);
        unsigned byte = (unsigned)(b * 1024 + j * 2) ^ (unsigned)((b & 7) << 4);
        *(uint2*)((unsigned char*)sX + byte) = make_uint2(lo, hi);
    }
    __syncthreads();

    const int wv = tid >> 6, lane = tid & 63;
    const int g = lane >> 4, m = lane & 15;
    const int kw = wv * 128;

    short8 fa[4];
#pragma unroll
    for (int s = 0; s < 4; ++s) {
        unsigned byte = (unsigned)(m * 1024 + (kw + s * 32 + g * 8) * 2)
                        ^ (unsigned)((m & 7) << 4);
        fa[s] = *(const short8*)((const unsigned char*)sX + byte);
    }

    const int kwmax = (250000 - k0) - 4;

#pragma unroll 2
    for (int nt = 0; nt < 8; ++nt) {
        const int o0 = nt * 16;
        const int orow = min(o0 + m, 119);
        const float* wr = w + (size_t)orow * 250000 + k0;
        f32x4 acc = {0.f, 0.f, 0.f, 0.f};
#pragma unroll
        for (int s = 0; s < 4; ++s) {
            int kc = kw + s * 32 + g * 8;
            int ka = (kc < kwmax) ? kc : kwmax;
            int kb = (kc + 4 < kwmax) ? kc + 4 : kwmax;
            float4 w0 = *(const float4*)(wr + ka);
            float4 w1 = *(const float4*)(wr + kb);
            union { unsigned u[4]; short8 v; } ub;
            ub.u[0] = pk2bf(w0.x, w0.y);
            ub.u[1] = pk2bf(w0.z, w0.w);
            ub.u[2] = pk2bf(w1.x, w1.y);
            ub.u[3] = pk2bf(w1.z, w1.w);
            acc = __builtin_amdgcn_mfma_f32_16x16x32_bf16(fa[s], ub.v, acc, 0, 0, 0);
        }
#pragma unroll
        for (int i = 0; i < 4; ++i) sY[wv][o0 + m][g * 4 + i] = acc[i];
    }
    __syncthreads();

    float* pp = partial + (size_t)blk * 1920;
    for (int i = tid; i < 1920; i += 256) {
        int o = i >> 4, b = i & 15;
        pp[i] = sY[0][o][b] + sY[1][o][b] + sY[2][o][b] + sY[3][o][b];
    }
}

// ---------------- fc0 reduce + bias + sigmoid ----------------
__global__ __launch_bounds__(256) void k_fc0red(const float* __restrict__ partial,
                                                const float* __restrict__ b0,
                                                float* __restrict__ h0) {
    const int tid = threadIdx.x;
    const int wv = tid >> 6, l = tid & 63;
    const int i = blockIdx.x * 4 + wv;
    float s = 0.0f;
    for (int c = l; c < FC0_NB; c += 64) s += partial[(size_t)c * 1920 + i];
    s += __shfl_xor(s, 1);
    s += __shfl_xor(s, 2);
    s += __shfl_xor(s, 4);
    s += __shfl_xor(s, 8);
    s += __shfl_xor(s, 16);
    s += __shfl_xor(s, 32);
    if (l == 0) {
        int o = i >> 4, bb = i & 15;
        h0[bb * 120 + o] = sigmf(s + b0[o]);
    }
}

__global__ __launch_bounds__(256) void k_fctail(const float* __restrict__ h0in,
                                                const float* __restrict__ fc1_w,
                                                const float* __restrict__ fc1_b,
                                                const float* __restrict__ fc2_w,
                                                const float* __restrict__ fc2_b,
                                                const float* __restrict__ gb1,
                                                const float* __restrict__ gb2,
                                                const float* __restrict__ base1,
                                                float* __restrict__ params) {
    __shared__ float sh0[1920];
    __shared__ float sh1[16][84];
    __shared__ float sout[16][10];
    const int tid = threadIdx.x;

    for (int i = tid; i < 1920; i += 256) sh0[i] = h0in[i];
    __syncthreads();

    for (int i = tid; i < 16 * 84; i += 256) {
        int bb = i / 84, o = i % 84;
        float a = fc1_b[o];
        for (int k = 0; k < 120; ++k) a = fmaf(sh0[bb * 120 + k], fc1_w[o * 120 + k], a);
        sh1[bb][o] = sigmf(a);
    }
    __syncthreads();

    for (int i = tid; i < 160; i += 256) {
        int bb = i / 10, o = i % 10;
        float a = fc2_b[o];
        for (int k = 0; k < 84; ++k) a = fmaf(sh1[bb][k], fc2_w[o * 84 + k], a);
        sout[bb][o] = a;
    }
    __syncthreads();

    if (tid < 16) {
        int bb = tid;
        float g1 = sout[bb][0] + gb1[0];
        float g2 = sout[bb][1] + gb2[0];
        float gain = 0.0f;
        for (int j = 0; j < 8; ++j) gain += sout[bb][2 + j] + base1[j];
        params[bb] = g1;
        params[16 + bb] = g2;
        params[32 + bb] = gain;
    }
}

__global__ __launch_bounds__(256) void k_final(const float* __restrict__ img,
                                               const float* __restrict__ params,
                                               float* __restrict__ out) {
    int idx = blockIdx.x * 256 + threadIdx.x;
    int p = idx * 4;
    int b = p >> 18;
    int hw = p & 262143;
    size_t base = ((size_t)b * 3) * 262144 + hw;

    float4 r = *(const float4*)(img + base);
    float4 g = *(const float4*)(img + base + 262144);
    float4 bl = *(const float4*)(img + base + 2 * 262144);
    float g1 = params[b], g2 = params[16 + b], gain = params[32 + b];

    float4 o0, o1, o2;
#pragma unroll
    for (int e = 0; e < 4; ++e) {
        float re = (&r.x)[e], ge = (&g.x)[e], be = (&bl.x)[e];
        float I = (re + ge + be) * (1.0f / 3.0f);
        float gv = (I > 0.5f) ? g2 : g1;
        (&o0.x)[e] = __powf(fminf(fmaxf(re * gain, EPSF), 1.0f), gv);
        (&o1.x)[e] = __powf(fminf(fmaxf(ge * gain, EPSF), 1.0f), gv);
        (&o2.x)[e] = __powf(fminf(fmaxf(be * gain, EPSF), 1.0f), gv);
    }
    *(float4*)(out + base) = o0;
    *(float4*)(out + base + 262144) = o1;
    *(float4*)(out + base + 2 * 262144) = o2;
}

// ---------------------------------------------------------------------------
extern "C" void kernel_launch(void* const* d_in, const int* in_sizes, int n_in,
                              void* d_out, int out_size, void* d_ws, size_t ws_size,
                              hipStream_t stream) {
    const float* img     = (const float*)d_in[0];
    const float* conv1_w = (const float*)d_in[1];
    const float* conv1_b = (const float*)d_in[2];
    const float* conv2_w = (const float*)d_in[3];
    const float* conv2_b = (const float*)d_in[4];
    const float* fc0_w   = (const float*)d_in[5];
    const float* fc0_b   = (const float*)d_in[6];
    const float* fc1_w   = (const float*)d_in[7];
    const float* fc1_b   = (const float*)d_in[8];
    const float* fc2_w   = (const float*)d_in[9];
    const float* fc2_b   = (const float*)d_in[10];
    const float* gb1     = (const float*)d_in[11];
    const float* gb2     = (const float*)d_in[12];
    const float* base1   = (const float*)d_in[13];

    float* outp = (float*)d_out;
    ushort_t* act1 = (ushort_t*)outp;           // 16*6*254*256 bf16 (padded rows)
    float* act2    = outp + 3121152;            // 4,000,000 f32
    float* partial = outp + 7121152;            // 938,880
    float* h0      = outp + 8060032;            // 1,920
    float* params  = (float*)d_ws;              // 48 floats

    k_conv1<<<dim3(4, 32, 16), dim3(256), 0, stream>>>(img, conv1_w, conv1_b, act1);
    k_conv2<<<dim3(2, 32, 16), dim3(256), 0, stream>>>(act1, conv2_w, conv2_b, act2);
    k_fc0<<<dim3(FC0_NB), dim3(256), 0, stream>>>(act2, fc0_w, partial);
    k_fc0red<<<dim3(480), dim3(256), 0, stream>>>(partial, fc0_b, h0);
    k_fctail<<<dim3(1), dim3(256), 0, stream>>>(h0, fc1_w, fc1_b, fc2_w, fc2_b,
                                                gb1, gb2, base1, params);
    k_final<<<dim3(4096), dim3(256), 0, stream>>>(img, params, outp);
}